// Round 7
// baseline (178.972 us; speedup 1.0000x reference)
//
#include <hip/hip_runtime.h>
#include <math.h>

#define NB 32
#define NH 256
#define NLC 1024
#define NLQ 256
#define NEGV (-1e30f)
#define LCHUNK 16  // column-stats l-chunks (each 64 rows)
#define KSPLIT 4   // tgemm split-K factor

typedef short short8 __attribute__((ext_vector_type(8)));
typedef float f32x4 __attribute__((ext_vector_type(4)));

__device__ inline short bf16_of(float f) {
  union { float f; unsigned u; } v;
  v.f = f;
  unsigned r = (v.u + 0x7fffu + ((v.u >> 16) & 1u)) >> 16;
  return (short)r;
}
__device__ inline float f_of(short s) {
  union { unsigned u; float f; } v;
  v.u = ((unsigned)(unsigned short)s) << 16;
  return v.f;
}
__device__ inline short8 cvt8(float4 a, float4 b) {
  short8 o;
  o[0] = bf16_of(a.x); o[1] = bf16_of(a.y); o[2] = bf16_of(a.z); o[3] = bf16_of(a.w);
  o[4] = bf16_of(b.x); o[5] = bf16_of(b.y); o[6] = bf16_of(b.z); o[7] = bf16_of(b.w);
  return o;
}

// ---- swizzled 128x32 bf16 LDS tile helpers (row = 64B, slot ^= (row>>1)&3) ----
__device__ inline void lds_w8(short* lds, int r, int c, short8 v) {
  int byteoff = (r << 6) + (((c ^ ((r >> 1) & 3)) & 3) << 4);
  *(short8*)((char*)lds + byteoff) = v;
}
__device__ inline short8 lds_r8(const short* lds, int R, int g) {
  int byteoff = (R << 6) + (((g ^ ((R >> 1) & 3)) & 3) << 4);
  return *(const short8*)((const char*)lds + byteoff);
}
// global_load_lds staging of a 128x32 bf16 tile from K-minor src (ld elements).
// Source group pre-permuted per-lane so linear LDS bytes match swizzled reads.
__device__ inline void stage_g(const short* src, int ld, short* lds, int t) {
  int L = t & 63, w = t >> 6;
  int cp = (L & 3) ^ ((L >> 3) & 3);
#pragma unroll
  for (int i = 0; i < 2; ++i) {
    int seg = w + i * 4;
    const short* g = src + (size_t)(seg * 16 + (L >> 2)) * ld + cp * 8;
    __builtin_amdgcn_global_load_lds(
        (const __attribute__((address_space(1))) unsigned int*)g,
        (__attribute__((address_space(3))) unsigned int*)(lds + seg * 512), 16,
        0, 0);
  }
}

#define GEMM_IDS                                       \
  int t = threadIdx.x, lane = t & 63, w = t >> 6;      \
  int ln = lane & 15, g = lane >> 4;                   \
  int wr = (w >> 1) << 6, wc = (w & 1) << 6;           \
  (void)wr; (void)wc;

#define MFMA_STEP(AS, BS)                                                      \
  {                                                                            \
    short8 af[4], bfr[4];                                                      \
    _Pragma("unroll") for (int mi = 0; mi < 4; ++mi) af[mi] =                  \
        lds_r8(AS, wr + mi * 16 + ln, g);                                      \
    _Pragma("unroll") for (int ni = 0; ni < 4; ++ni) bfr[ni] =                 \
        lds_r8(BS, wc + ni * 16 + ln, g);                                      \
    _Pragma("unroll") for (int mi = 0; mi < 4; ++mi)                           \
        _Pragma("unroll") for (int ni = 0; ni < 4; ++ni) acc[mi][ni] =         \
            __builtin_amdgcn_mfma_f32_16x16x32_bf16(af[mi], bfr[ni],           \
                                                    acc[mi][ni], 0, 0, 0);     \
  }

// ---------------- prep: Ct_lh[l][h] = bf16(C[h][l]) ----------------
__global__ __launch_bounds__(256) void k_prep_c(const float* __restrict__ C,
                                                short* __restrict__ Ct_lh) {
  __shared__ float Ts[64][65];
  int b = blockIdx.z, h0 = blockIdx.y << 6, l0 = blockIdx.x << 6;
  int t = threadIdx.x;
  int hr = t >> 4, lc = (t & 15) << 2;
  const float* Cb = C + ((size_t)b * NH + h0) * NLC + l0;
#pragma unroll
  for (int i = 0; i < 4; ++i) {
    float4 v = *(const float4*)&Cb[(size_t)(hr + i * 16) * NLC + lc];
    Ts[hr + i * 16][lc + 0] = v.x;
    Ts[hr + i * 16][lc + 1] = v.y;
    Ts[hr + i * 16][lc + 2] = v.z;
    Ts[hr + i * 16][lc + 3] = v.w;
  }
  __syncthreads();
  int lr = t >> 2, hc = (t & 3) << 4;
  short* dst = &Ct_lh[((size_t)b * NLC + l0 + lr) * NH + h0 + hc];
  short8 o0, o1;
#pragma unroll
  for (int j = 0; j < 8; ++j) o0[j] = bf16_of(Ts[hc + j][lr]);
#pragma unroll
  for (int j = 0; j < 8; ++j) o1[j] = bf16_of(Ts[hc + 8 + j][lr]);
  *(short8*)dst = o0;
  *(short8*)(dst + 8) = o1;
}

// ---- prep: Qtw3[m][h] = bf16(Q[h][m]*w3[h]); also Qb_hm[h][m] = bf16(Q) ----
__global__ __launch_bounds__(256) void k_prep_q(const float* __restrict__ Q,
                                                const float* __restrict__ w,
                                                short* __restrict__ Qtw3,
                                                short* __restrict__ Qb_hm) {
  __shared__ float Ts[64][65];
  int b = blockIdx.z, h0 = blockIdx.y << 6, m0 = blockIdx.x << 6;
  int t = threadIdx.x;
  int hr = t >> 4, mc = (t & 15) << 2;
  const float* w3 = w + 2 * NH;
  const float* Qb = Q + ((size_t)b * NH + h0) * NLQ + m0;
#pragma unroll
  for (int i = 0; i < 4; ++i) {
    int h = hr + i * 16;
    float w3v = w3[h0 + h];
    float4 v = *(const float4*)&Qb[(size_t)h * NLQ + mc];
    short4 qb;
    qb.x = bf16_of(v.x); qb.y = bf16_of(v.y);
    qb.z = bf16_of(v.z); qb.w = bf16_of(v.w);
    *(short4*)&Qb_hm[((size_t)b * NH + h0 + h) * NLQ + m0 + mc] = qb;
    Ts[h][mc + 0] = v.x * w3v;
    Ts[h][mc + 1] = v.y * w3v;
    Ts[h][mc + 2] = v.z * w3v;
    Ts[h][mc + 3] = v.w * w3v;
  }
  __syncthreads();
  int mr = t >> 2, hc = (t & 3) << 4;
  short* dst = &Qtw3[((size_t)b * NLQ + m0 + mr) * NH + h0 + hc];
  short8 o0, o1;
#pragma unroll
  for (int j = 0; j < 8; ++j) o0[j] = bf16_of(Ts[hc + j][mr]);
#pragma unroll
  for (int j = 0; j < 8; ++j) o1[j] = bf16_of(Ts[hc + 8 + j][mr]);
  *(short8*)dst = o0;
  *(short8*)(dst + 8) = o1;
}

// ---------------- prep: plain f32 -> bf16 copies ----------------
__global__ __launch_bounds__(256) void k_prep_bf16(const float* __restrict__ X,
                                                   short* __restrict__ Y) {
  size_t i = ((size_t)blockIdx.x * 256 + threadIdx.x) * 8;
  float4 v0 = *(const float4*)&X[i];
  float4 v1 = *(const float4*)&X[i + 4];
  *(short8*)&Y[i] = cvt8(v0, v1);
}

// s1[b][l] = sum_h C[b][h][l] * w1[h]
__global__ __launch_bounds__(256) void k_s1(const float* __restrict__ C,
                                            const float* __restrict__ w,
                                            float* __restrict__ s1) {
  int b = blockIdx.x >> 2;
  int l = ((blockIdx.x & 3) << 8) + threadIdx.x;
  const float* Cb = C + (size_t)b * NH * NLC;
  float acc = 0.f;
#pragma unroll 8
  for (int h = 0; h < NH; ++h) acc += Cb[(size_t)h * NLC + l] * w[h];
  s1[b * NLC + l] = acc;
}

// s2[b][m] = sum_h Q[b][h][m] * w2[h]
__global__ __launch_bounds__(256) void k_s2(const float* __restrict__ Q,
                                            const float* __restrict__ w,
                                            float* __restrict__ s2) {
  int b = blockIdx.x;
  int m = threadIdx.x;
  const float* Qb = Q + (size_t)b * NH * NLQ;
  const float* w2 = w + NH;
  float acc = 0.f;
#pragma unroll 8
  for (int h = 0; h < NH; ++h) acc += Qb[(size_t)h * NLQ + m] * w2[h];
  s2[b * NLQ + m] = acc;
}

// ------- S = Ct_lh @ Qtw3^T + s1 + s2  (M=l, N=m, K=h); 2-phase dbuf -------
__global__ __launch_bounds__(256) void k_sgemm(
    const short* __restrict__ Ct_lh, const short* __restrict__ Qtw3,
    const float* __restrict__ s1, const float* __restrict__ s2,
    float* __restrict__ S) {
  __shared__ short As[2][4096], Bs[2][4096];
  int b = blockIdx.z, l0 = blockIdx.y << 7, m0 = blockIdx.x << 7;
  GEMM_IDS
  const short* Ag = Ct_lh + ((size_t)b * NLC + l0) * NH;
  const short* Bg = Qtw3 + ((size_t)b * NLQ + m0) * NH;
  f32x4 acc[4][4] = {};
  stage_g(Ag, NH, As[0], t);
  stage_g(Bg, NH, Bs[0], t);
  __syncthreads();
  int cur = 0;
  for (int kn = 32; kn <= NH; kn += 32) {
    if (kn < NH) {
      stage_g(Ag + kn, NH, As[cur ^ 1], t);
      stage_g(Bg + kn, NH, Bs[cur ^ 1], t);
    }
    MFMA_STEP(As[cur], Bs[cur])
    __syncthreads();
    cur ^= 1;
  }
#pragma unroll
  for (int mi = 0; mi < 4; ++mi)
#pragma unroll
    for (int ni = 0; ni < 4; ++ni)
#pragma unroll
      for (int r = 0; r < 4; ++r) {
        int l = l0 + wr + mi * 16 + g * 4 + r;
        int m = m0 + wc + ni * 16 + ln;
        S[((size_t)b * NLC + l) * NLQ + m] =
            acc[mi][ni][r] + s1[b * NLC + l] + s2[b * NLQ + m];
      }
}

// per-column (over l) masked max & sum-exp partials, one 64-row chunk per block.
__global__ __launch_bounds__(256) void k_colpart(const float* __restrict__ S,
                                                 const int* __restrict__ cmask,
                                                 float* __restrict__ pmax,
                                                 float* __restrict__ psum) {
  int idx = blockIdx.x;  // ((b*4 + mb)*LCHUNK + chunk)
  int chunk = idx & (LCHUNK - 1);
  int mb = (idx >> 4) & 3;
  int b = idx >> 6;
  int m0 = mb << 6;
  int tx = threadIdx.x & 63, ty = threadIdx.x >> 6;
  const float* Sb = S + (size_t)b * NLC * NLQ + (size_t)(chunk * 64) * NLQ;
  const int* cm = cmask + b * NLC + chunk * 64;
  float mx = -INFINITY, sm = 0.f;
#pragma unroll 4
  for (int l = ty; l < 64; l += 4) {
    float x = Sb[(size_t)l * NLQ + m0 + tx] + (cm[l] ? 0.f : NEGV);
    float nmx = fmaxf(mx, x);
    sm = sm * expf(mx - nmx) + expf(x - nmx);
    mx = nmx;
  }
  __shared__ float smx[4][64], ssm[4][64];
  smx[ty][tx] = mx;
  ssm[ty][tx] = sm;
  __syncthreads();
  if (ty == 0) {
#pragma unroll
    for (int r = 1; r < 4; ++r) {
      float m2 = smx[r][tx], s2 = ssm[r][tx];
      float nm = fmaxf(mx, m2);
      sm = sm * expf(mx - nm) + s2 * expf(m2 - nm);
      mx = nm;
    }
    int m = (b << 8) + m0 + tx;  // global column id
    pmax[(size_t)m * LCHUNK + chunk] = mx;
    psum[(size_t)m * LCHUNK + chunk] = sm;
  }
}

// combine LCHUNK partials per column -> cmax, cinv. One thread per column.
__global__ __launch_bounds__(256) void k_colfin(const float* __restrict__ pmax,
                                                const float* __restrict__ psum,
                                                float* __restrict__ cmax,
                                                float* __restrict__ cinv) {
  int m = blockIdx.x * 256 + threadIdx.x;  // [0, NB*NLQ)
  const float* pm = pmax + (size_t)m * LCHUNK;
  const float* ps = psum + (size_t)m * LCHUNK;
  float mx = pm[0], sm = ps[0];
#pragma unroll
  for (int c = 1; c < LCHUNK; ++c) {
    float m2 = pm[c], s2 = ps[c];
    float nm = fmaxf(mx, m2);
    sm = sm * expf(mx - nm) + s2 * expf(m2 - nm);
    mx = nm;
  }
  cmax[m] = mx;
  cinv[m] = 1.0f / sm;
}

// ------ Tp[ks][b][h][m] = sum_{l in chunk ks} C[h][l] * S_col[l][m] ------
// split-K partials (f32); M=h, N=m, K=l chunk of 256; 2-phase dbuf
// (loads for tile t+1 issue before MFMA on t; convert/exp+ds_write after).
__global__ __launch_bounds__(256) void k_tgemm(
    const float* __restrict__ C, const float* __restrict__ S,
    const int* __restrict__ cmask, const float* __restrict__ cmax,
    const float* __restrict__ cinv, float* __restrict__ Tp) {
  __shared__ short As[2][4096], Bs[2][4096];
  int b = blockIdx.z;
  int ks = blockIdx.y;
  int h0 = (blockIdx.x & 1) << 7;
  int m0 = (blockIdx.x >> 1) << 7;
  GEMM_IDS
  const float* Cb = C + ((size_t)b * NH + h0) * NLC;
  const float* Sb = S + (size_t)b * NLC * NLQ;
  const float* cmx = cmax + b * NLQ + m0;
  const float* civ = cinv + b * NLQ + m0;
  const int* cm = cmask + b * NLC;
  f32x4 acc[4][4] = {};
  int kbeg = ks * (NLC / KSPLIT), kend = kbeg + NLC / KSPLIT;
  int ca = lane & 3;
  int lloc = t >> 3, g2 = lloc >> 3, kin = lloc & 7;
  int mbase = (t & 7) << 2;

  {  // prologue: stage tile kbeg into buf 0
#pragma unroll
    for (int i = 0; i < 2; ++i) {
      int seg = w + i * 4, r = seg * 16 + (lane >> 2);
      const float* src = &Cb[(size_t)r * NLC + kbeg + ca * 8];
      float4 v0 = *(const float4*)src;
      float4 v1 = *(const float4*)(src + 4);
      lds_w8(As[0], r, ca, cvt8(v0, v1));
    }
    int l = kbeg + lloc;
    float cmf = (float)cm[l];
    const float* srow = &Sb[(size_t)l * NLQ + m0];
#pragma unroll
    for (int mi4 = 0; mi4 < 4; ++mi4) {
      int m = mbase + (mi4 << 5);
      float4 sv = *(const float4*)&srow[m];
      float p[4];
      p[0] = expf(sv.x - cmx[m + 0]) * civ[m + 0] * cmf;
      p[1] = expf(sv.y - cmx[m + 1]) * civ[m + 1] * cmf;
      p[2] = expf(sv.z - cmx[m + 2]) * civ[m + 2] * cmf;
      p[3] = expf(sv.w - cmx[m + 3]) * civ[m + 3] * cmf;
#pragma unroll
      for (int j = 0; j < 4; ++j) {
        int R = m + j;
        int byteoff =
            (R << 6) + (((g2 ^ ((R >> 1) & 3)) & 3) << 4) + (kin << 1);
        *(short*)((char*)Bs[0] + byteoff) = bf16_of(p[j]);
      }
    }
  }
  __syncthreads();
  int cur = 0;
  for (int kn = kbeg + 32; kn <= kend; kn += 32) {
    bool has = kn < kend;
    float4 av0[2], av1[2], svn[4];
    float cmf = 0.f;
    if (has) {
#pragma unroll
      for (int i = 0; i < 2; ++i) {
        int seg = w + i * 4, r = seg * 16 + (lane >> 2);
        const float* src = &Cb[(size_t)r * NLC + kn + ca * 8];
        av0[i] = *(const float4*)src;
        av1[i] = *(const float4*)(src + 4);
      }
      int l = kn + lloc;
      cmf = (float)cm[l];
      const float* srow = &Sb[(size_t)l * NLQ + m0];
#pragma unroll
      for (int mi4 = 0; mi4 < 4; ++mi4)
        svn[mi4] = *(const float4*)&srow[mbase + (mi4 << 5)];
    }
    MFMA_STEP(As[cur], Bs[cur])
    if (has) {
#pragma unroll
      for (int i = 0; i < 2; ++i) {
        int seg = w + i * 4, r = seg * 16 + (lane >> 2);
        lds_w8(As[cur ^ 1], r, ca, cvt8(av0[i], av1[i]));
      }
#pragma unroll
      for (int mi4 = 0; mi4 < 4; ++mi4) {
        int m = mbase + (mi4 << 5);
        float p[4];
        p[0] = expf(svn[mi4].x - cmx[m + 0]) * civ[m + 0] * cmf;
        p[1] = expf(svn[mi4].y - cmx[m + 1]) * civ[m + 1] * cmf;
        p[2] = expf(svn[mi4].z - cmx[m + 2]) * civ[m + 2] * cmf;
        p[3] = expf(svn[mi4].w - cmx[m + 3]) * civ[m + 3] * cmf;
#pragma unroll
        for (int j = 0; j < 4; ++j) {
          int R = m + j;
          int byteoff =
              (R << 6) + (((g2 ^ ((R >> 1) & 3)) & 3) << 4) + (kin << 1);
          *(short*)((char*)Bs[cur ^ 1] + byteoff) = bf16_of(p[j]);
        }
      }
    }
    __syncthreads();
    cur ^= 1;
  }
  float* dst = Tp + ((size_t)ks * NB + b) * NH * NLQ;
#pragma unroll
  for (int mi = 0; mi < 4; ++mi)
#pragma unroll
    for (int ni = 0; ni < 4; ++ni)
#pragma unroll
      for (int r = 0; r < 4; ++r) {
        int h = h0 + wr + mi * 16 + g * 4 + r;
        int m = m0 + wc + ni * 16 + ln;
        dst[(size_t)h * NLQ + m] = acc[mi][ni][r];
      }
}

// reduce KSPLIT partials -> bf16 Tt[b][h][m]
__global__ __launch_bounds__(256) void k_tfin(const float* __restrict__ Tp,
                                              short* __restrict__ Tt) {
  size_t i = ((size_t)blockIdx.x * 256 + threadIdx.x) * 4;
  const size_t stride = (size_t)NB * NH * NLQ;
  float4 s = *(const float4*)&Tp[i];
#pragma unroll
  for (int ks = 1; ks < KSPLIT; ++ks) {
    float4 v = *(const float4*)&Tp[i + ks * stride];
    s.x += v.x; s.y += v.y; s.z += v.z; s.w += v.w;
  }
  short4 o;
  o.x = bf16_of(s.x);
  o.y = bf16_of(s.y);
  o.z = bf16_of(s.z);
  o.w = bf16_of(s.w);
  *(short4*)&Tt[i] = o;
}

// ---- row softmax, IN PLACE: writes bf16 P_row into the first 512B of each
// 1KB f32 S row (each wave reads its whole row into regs before storing).
__global__ __launch_bounds__(256) void k_rowsoft(float* __restrict__ S,
                                                 const int* __restrict__ qmask) {
  int wave = threadIdx.x >> 6, lane = threadIdx.x & 63;
  int idx = (blockIdx.x << 2) + wave;  // row id in [0, NB*NLC)
  int b = idx >> 10;
  float* row = S + (size_t)idx * NLQ;
  const int* qm = qmask + b * NLQ;
  int m4 = lane << 2;
  float4 v = *(const float4*)&row[m4];
  int4 q = *(const int4*)&qm[m4];
  float x0 = v.x + (q.x ? 0.f : NEGV);
  float x1 = v.y + (q.y ? 0.f : NEGV);
  float x2 = v.z + (q.z ? 0.f : NEGV);
  float x3 = v.w + (q.w ? 0.f : NEGV);
  float mx = fmaxf(fmaxf(x0, x1), fmaxf(x2, x3));
#pragma unroll
  for (int off = 32; off > 0; off >>= 1) mx = fmaxf(mx, __shfl_xor(mx, off));
  float p0 = expf(x0 - mx), p1 = expf(x1 - mx);
  float p2 = expf(x2 - mx), p3 = expf(x3 - mx);
  float sm = p0 + p1 + p2 + p3;
#pragma unroll
  for (int off = 32; off > 0; off >>= 1) sm += __shfl_xor(sm, off);
  float iv = 1.0f / sm;
  short4 o;
  o.x = bf16_of(p0 * iv);
  o.y = bf16_of(p1 * iv);
  o.z = bf16_of(p2 * iv);
  o.w = bf16_of(p3 * iv);
  *(short4*)((short*)row + m4) = o;
}

// ---- [A | Ct*Bv][l][h] = f(sum_m P_row[l][m] * X[h][m]); 2-phase dbuf ----
__global__ __launch_bounds__(256) void k_abgemm(
    const short* __restrict__ Prow, const short* __restrict__ Qb_hm,
    const short* __restrict__ Tt, const short* __restrict__ Ct_lh,
    short* __restrict__ A_lh, short* __restrict__ CtBv_lh) {
  __shared__ short As[2][4096], Bs[2][4096];
  int b = blockIdx.z, l0 = blockIdx.y << 7, nb = blockIdx.x;
  GEMM_IDS
  const short* Ag = Prow + ((size_t)b * NLC + l0) * 512;
  const short* Bbase = (nb < 2)
                           ? Qb_hm + ((size_t)b * NH + nb * 128) * NLQ
                           : Tt + ((size_t)b * NH + (nb - 2) * 128) * NLQ;
  f32x4 acc[4][4] = {};
  stage_g(Ag, 512, As[0], t);
  stage_g(Bbase, NLQ, Bs[0], t);
  __syncthreads();
  int cur = 0;
  for (int kn = 32; kn <= NLQ; kn += 32) {
    if (kn < NLQ) {
      stage_g(Ag + kn, 512, As[cur ^ 1], t);
      stage_g(Bbase + kn, NLQ, Bs[cur ^ 1], t);
    }
    MFMA_STEP(As[cur], Bs[cur])
    __syncthreads();
    cur ^= 1;
  }
  int hbase = (nb & 1) << 7;
  if (nb < 2) {
#pragma unroll
    for (int mi = 0; mi < 4; ++mi)
#pragma unroll
      for (int ni = 0; ni < 4; ++ni)
#pragma unroll
        for (int r = 0; r < 4; ++r) {
          int l = l0 + wr + mi * 16 + g * 4 + r;
          int h = hbase + wc + ni * 16 + ln;
          A_lh[((size_t)b * NLC + l) * NH + h] = bf16_of(acc[mi][ni][r]);
        }
  } else {
#pragma unroll
    for (int mi = 0; mi < 4; ++mi)
#pragma unroll
      for (int ni = 0; ni < 4; ++ni)
#pragma unroll
        for (int r = 0; r < 4; ++r) {
          int l = l0 + wr + mi * 16 + g * 4 + r;
          int h = hbase + wc + ni * 16 + ln;
          size_t off = ((size_t)b * NLC + l) * NH + h;
          CtBv_lh[off] = bf16_of(f_of(Ct_lh[off]) * acc[mi][ni][r]);
        }
  }
}

// -------- out[h][l] = relu(b + sum_f W[h][f]*cat[l][f]); 2-phase dbuf --------
// cat regions along f: [Ct | A | Ct*A | Ct*Bv]; Wb is bf16 W_res.
__global__ __launch_bounds__(256) void k_out(
    const short* __restrict__ Wb, const short* __restrict__ Ct_lh,
    const short* __restrict__ A_lh, const short* __restrict__ CtBv_lh,
    const float* __restrict__ br, float* __restrict__ out) {
  __shared__ short As[2][4096], Bs[2][4096];
  int b = blockIdx.z, h0 = blockIdx.y << 7, l0 = blockIdx.x << 7;
  GEMM_IDS
  const short* Wg = Wb + (size_t)h0 * (4 * NH);
  size_t boff = ((size_t)b * NLC + l0) * NH;
  f32x4 acc[4][4] = {};
  stage_g(Wg, 4 * NH, As[0], t);
  stage_g(Ct_lh + boff, NH, Bs[0], t);  // tile 0 is region 0 (Ct)
  __syncthreads();
  int cur = 0;
  for (int kn = 32; kn <= 4 * NH; kn += 32) {
    bool has = kn < 4 * NH;
    int regn = kn >> 8, kon = kn & 255;
    short8 x1[2], x2[2];
    int ca = lane & 3;
    if (has) {
      stage_g(Wg + kn, 4 * NH, As[cur ^ 1], t);
      if (regn != 2) {
        const short* base = (regn == 0) ? Ct_lh : (regn == 1) ? A_lh : CtBv_lh;
        stage_g(base + boff + kon, NH, Bs[cur ^ 1], t);
      } else {
#pragma unroll
        for (int i = 0; i < 2; ++i) {
          int seg = w + i * 4, r = seg * 16 + (lane >> 2);
          size_t off = boff + (size_t)r * NH + kon + ca * 8;
          x1[i] = *(const short8*)&Ct_lh[off];
          x2[i] = *(const short8*)&A_lh[off];
        }
      }
    }
    MFMA_STEP(As[cur], Bs[cur])
    if (has && regn == 2) {
#pragma unroll
      for (int i = 0; i < 2; ++i) {
        int seg = w + i * 4, r = seg * 16 + (lane >> 2);
        short8 o;
#pragma unroll
        for (int j = 0; j < 8; ++j)
          o[j] = bf16_of(f_of(x1[i][j]) * f_of(x2[i][j]));
        lds_w8(Bs[cur ^ 1], r, ca, o);
      }
    }
    __syncthreads();
    cur ^= 1;
  }
#pragma unroll
  for (int mi = 0; mi < 4; ++mi)
#pragma unroll
    for (int ni = 0; ni < 4; ++ni) {
      int h = h0 + wr + mi * 16 + g * 4;
      int l = l0 + wc + ni * 16 + ln;
#pragma unroll
      for (int r = 0; r < 4; ++r) {
        float bias = br[h + r];
        out[((size_t)b * NH + h + r) * NLC + l] =
            fmaxf(acc[mi][ni][r] + bias, 0.f);
      }
    }
}

extern "C" void kernel_launch(void* const* d_in, const int* in_sizes, int n_in,
                              void* d_out, int out_size, void* d_ws,
                              size_t ws_size, hipStream_t stream) {
  (void)in_sizes;
  (void)n_in;
  (void)out_size;
  (void)ws_size;
  const float* C = (const float*)d_in[0];
  const float* Q = (const float*)d_in[1];
  const int* cmask = (const int*)d_in[2];
  const int* qmask = (const int*)d_in[3];
  const float* w = (const float*)d_in[4];
  const float* W = (const float*)d_in[5];
  const float* br = (const float*)d_in[6];
  float* out = (float*)d_out;

  char* p = (char*)d_ws;
  float* S = (float*)p;       p += (size_t)NB * NLC * NLQ * 4;   // 33.6 MB
  short* Ct_lh = (short*)p;   p += (size_t)NB * NLC * NH * 2;    // 16.8 MB
  short* A_lh = (short*)p;    p += (size_t)NB * NLC * NH * 2;    // 16.8 MB
  short* CtBv_lh = (short*)p; p += (size_t)NB * NLC * NH * 2;    // 16.8 MB
  short* Tt = (short*)p;      p += (size_t)NB * NH * NLQ * 2;    // 4.2 MB
  short* Qtw3 = (short*)p;    p += (size_t)NB * NLQ * NH * 2;    // 4.2 MB
  short* Qb_hm = (short*)p;   p += (size_t)NB * NH * NLQ * 2;    // 4.2 MB
  short* Wb = (short*)p;      p += (size_t)NH * 4 * NH * 2;      // 0.5 MB
  float* s1 = (float*)p;      p += (size_t)NB * NLC * 4;
  float* s2 = (float*)p;      p += (size_t)NB * NLQ * 4;
  float* cmax = (float*)p;    p += (size_t)NB * NLQ * 4;
  float* cinv = (float*)p;    p += (size_t)NB * NLQ * 4;
  float* pmax = (float*)p;    p += (size_t)NB * NLQ * LCHUNK * 4;
  float* psum = (float*)p;    p += (size_t)NB * NLQ * LCHUNK * 4;
  // tgemm split-K partials: reuse A_lh+CtBv_lh (33.6 MB, dead until abgemm).
  float* Tp = (float*)A_lh;
  // in-place row-softmax result: bf16 P_row lives in S (row stride 512 shorts)
  short* Prow = (short*)S;

  k_prep_c<<<dim3(NLC / 64, NH / 64, NB), dim3(256), 0, stream>>>(C, Ct_lh);
  k_prep_q<<<dim3(NLQ / 64, NH / 64, NB), dim3(256), 0, stream>>>(Q, w, Qtw3,
                                                                  Qb_hm);
  k_prep_bf16<<<dim3(NH * 4 * NH / 2048), dim3(256), 0, stream>>>(W, Wb);
  k_s1<<<dim3(NB * (NLC / 256)), dim3(256), 0, stream>>>(C, w, s1);
  k_s2<<<dim3(NB), dim3(256), 0, stream>>>(Q, w, s2);
  k_sgemm<<<dim3(NLQ / 128, NLC / 128, NB), dim3(256), 0, stream>>>(
      Ct_lh, Qtw3, s1, s2, S);
  k_colpart<<<dim3(NB * 4 * LCHUNK), dim3(256), 0, stream>>>(S, cmask, pmax,
                                                             psum);
  k_colfin<<<dim3(NB * NLQ / 256), dim3(256), 0, stream>>>(pmax, psum, cmax,
                                                           cinv);
  // tgemm/tfin read f32 S -> must precede the in-place rowsoft overwrite.
  k_tgemm<<<dim3(4, KSPLIT, NB), dim3(256), 0, stream>>>(C, S, cmask, cmax,
                                                         cinv, Tp);
  k_tfin<<<dim3(NB * NH * NLQ / 1024), dim3(256), 0, stream>>>(Tp, Tt);
  k_rowsoft<<<dim3(NB * NLC / 4), dim3(256), 0, stream>>>(S, qmask);
  k_abgemm<<<dim3(4, NLC / 128, NB), dim3(256), 0, stream>>>(
      Prow, Qb_hm, Tt, Ct_lh, A_lh, CtBv_lh);
  k_out<<<dim3(NLC / 128, NH / 128, NB), dim3(256), 0, stream>>>(
      Wb, Ct_lh, A_lh, CtBv_lh, br, out);
}

// Round 8
// 153.814 us; speedup vs baseline: 1.1636x; 1.1636x over previous
//
#include <hip/hip_runtime.h>
#include <math.h>

#define NB 32
#define NH 256
#define NLC 1024
#define NLQ 256
#define NEGV (-1e30f)
#define LCHUNK 16  // column-stats l-chunks (each 64 rows)
#define KSPLIT 4   // tgemm split-K factor

typedef short short8 __attribute__((ext_vector_type(8)));
typedef float f32x4 __attribute__((ext_vector_type(4)));

__device__ inline short bf16_of(float f) {
  union { float f; unsigned u; } v;
  v.f = f;
  unsigned r = (v.u + 0x7fffu + ((v.u >> 16) & 1u)) >> 16;
  return (short)r;
}
__device__ inline float f_of(short s) {
  union { unsigned u; float f; } v;
  v.u = ((unsigned)(unsigned short)s) << 16;
  return v.f;
}
__device__ inline short8 cvt8(float4 a, float4 b) {
  short8 o;
  o[0] = bf16_of(a.x); o[1] = bf16_of(a.y); o[2] = bf16_of(a.z); o[3] = bf16_of(a.w);
  o[4] = bf16_of(b.x); o[5] = bf16_of(b.y); o[6] = bf16_of(b.z); o[7] = bf16_of(b.w);
  return o;
}

// ---- swizzled 128x32 bf16 LDS tile helpers (row = 64B, slot ^= (row>>1)&3) ----
__device__ inline void lds_w8(short* lds, int r, int c, short8 v) {
  int byteoff = (r << 6) + (((c ^ ((r >> 1) & 3)) & 3) << 4);
  *(short8*)((char*)lds + byteoff) = v;
}
__device__ inline short8 lds_r8(const short* lds, int R, int g) {
  int byteoff = (R << 6) + (((g ^ ((R >> 1) & 3)) & 3) << 4);
  return *(const short8*)((const char*)lds + byteoff);
}
// global_load_lds staging of a 128x32 bf16 tile from K-minor src (ld elements).
// Source group pre-permuted per-lane so linear LDS bytes match swizzled reads.
__device__ inline void stage_g(const short* src, int ld, short* lds, int t) {
  int L = t & 63, w = t >> 6;
  int cp = (L & 3) ^ ((L >> 3) & 3);
#pragma unroll
  for (int i = 0; i < 2; ++i) {
    int seg = w + i * 4;
    const short* g = src + (size_t)(seg * 16 + (L >> 2)) * ld + cp * 8;
    __builtin_amdgcn_global_load_lds(
        (const __attribute__((address_space(1))) unsigned int*)g,
        (__attribute__((address_space(3))) unsigned int*)(lds + seg * 512), 16,
        0, 0);
  }
}

#define GEMM_IDS                                       \
  int t = threadIdx.x, lane = t & 63, w = t >> 6;      \
  int ln = lane & 15, g = lane >> 4;                   \
  int wr = (w >> 1) << 6, wc = (w & 1) << 6;           \
  (void)wr; (void)wc;

#define MFMA_STEP(AS, BS)                                                      \
  {                                                                            \
    short8 af[4], bfr[4];                                                      \
    _Pragma("unroll") for (int mi = 0; mi < 4; ++mi) af[mi] =                  \
        lds_r8(AS, wr + mi * 16 + ln, g);                                      \
    _Pragma("unroll") for (int ni = 0; ni < 4; ++ni) bfr[ni] =                 \
        lds_r8(BS, wc + ni * 16 + ln, g);                                      \
    _Pragma("unroll") for (int mi = 0; mi < 4; ++mi)                           \
        _Pragma("unroll") for (int ni = 0; ni < 4; ++ni) acc[mi][ni] =         \
            __builtin_amdgcn_mfma_f32_16x16x32_bf16(af[mi], bfr[ni],           \
                                                    acc[mi][ni], 0, 0, 0);     \
  }

// ---- prep: Ct_lh[l][h] = bf16(C[h][l]); s1 partials per 64-h slice ----
__global__ __launch_bounds__(256) void k_prep_c(const float* __restrict__ C,
                                                const float* __restrict__ w,
                                                short* __restrict__ Ct_lh,
                                                float* __restrict__ s1p) {
  __shared__ float Ts[64][65];
  __shared__ float red[4][64];
  int b = blockIdx.z, h0 = blockIdx.y << 6, l0 = blockIdx.x << 6;
  int t = threadIdx.x;
  int hr = t >> 4, lc = (t & 15) << 2;
  const float* Cb = C + ((size_t)b * NH + h0) * NLC + l0;
#pragma unroll
  for (int i = 0; i < 4; ++i) {
    float4 v = *(const float4*)&Cb[(size_t)(hr + i * 16) * NLC + lc];
    Ts[hr + i * 16][lc + 0] = v.x;
    Ts[hr + i * 16][lc + 1] = v.y;
    Ts[hr + i * 16][lc + 2] = v.z;
    Ts[hr + i * 16][lc + 3] = v.w;
  }
  __syncthreads();
  int lr = t >> 2, hc = (t & 3) << 4;
  short* dst = &Ct_lh[((size_t)b * NLC + l0 + lr) * NH + h0 + hc];
  short8 o0, o1;
#pragma unroll
  for (int j = 0; j < 8; ++j) o0[j] = bf16_of(Ts[hc + j][lr]);
#pragma unroll
  for (int j = 0; j < 8; ++j) o1[j] = bf16_of(Ts[hc + 8 + j][lr]);
  *(short8*)dst = o0;
  *(short8*)(dst + 8) = o1;
  // s1 partial: sum over this block's 64 h of C[h][l]*w1[h]
  int q = t >> 6, lq = t & 63;
  float a = 0.f;
#pragma unroll
  for (int j = 0; j < 16; ++j) a += Ts[(q << 4) + j][lq] * w[h0 + (q << 4) + j];
  red[q][lq] = a;
  __syncthreads();
  if (q == 0)
    s1p[((size_t)blockIdx.y * NB + b) * NLC + l0 + lq] =
        red[0][lq] + red[1][lq] + red[2][lq] + red[3][lq];
}

// ---- prep: Qtw3[m][h]=bf16(Q[h][m]*w3[h]); Qb_hm=bf16(Q); s2 partials ----
__global__ __launch_bounds__(256) void k_prep_q(const float* __restrict__ Q,
                                                const float* __restrict__ w,
                                                short* __restrict__ Qtw3,
                                                short* __restrict__ Qb_hm,
                                                float* __restrict__ s2p) {
  __shared__ float Ts[64][65];
  __shared__ float red[4][64];
  int b = blockIdx.z, h0 = blockIdx.y << 6, m0 = blockIdx.x << 6;
  int t = threadIdx.x;
  int hr = t >> 4, mc = (t & 15) << 2;
  const float* w3 = w + 2 * NH;
  const float* Qb = Q + ((size_t)b * NH + h0) * NLQ + m0;
#pragma unroll
  for (int i = 0; i < 4; ++i) {
    int h = hr + i * 16;
    float w3v = w3[h0 + h];
    float4 v = *(const float4*)&Qb[(size_t)h * NLQ + mc];
    short4 qb;
    qb.x = bf16_of(v.x); qb.y = bf16_of(v.y);
    qb.z = bf16_of(v.z); qb.w = bf16_of(v.w);
    *(short4*)&Qb_hm[((size_t)b * NH + h0 + h) * NLQ + m0 + mc] = qb;
    Ts[h][mc + 0] = v.x * w3v;
    Ts[h][mc + 1] = v.y * w3v;
    Ts[h][mc + 2] = v.z * w3v;
    Ts[h][mc + 3] = v.w * w3v;
  }
  __syncthreads();
  int mr = t >> 2, hc = (t & 3) << 4;
  short* dst = &Qtw3[((size_t)b * NLQ + m0 + mr) * NH + h0 + hc];
  short8 o0, o1;
#pragma unroll
  for (int j = 0; j < 8; ++j) o0[j] = bf16_of(Ts[hc + j][mr]);
#pragma unroll
  for (int j = 0; j < 8; ++j) o1[j] = bf16_of(Ts[hc + 8 + j][mr]);
  *(short8*)dst = o0;
  *(short8*)(dst + 8) = o1;
  // s2 partial: note Ts holds Q*w3, so divide back ... instead recompute from
  // the raw value: Ts[h][m]/w3 is risky (w3 may be 0). Use a second pass read.
  // Cheaper: accumulate from global again is wasteful; instead store raw Q in
  // red path: recompute using w2 directly from Ts is impossible -> use Qb? No:
  // Q tile is still in L1/LDS as Ts*w3. Simplest exact: reload the 16 values.
  int q = t >> 6, mq = t & 63;
  const float* w2 = w + NH;
  float a = 0.f;
#pragma unroll
  for (int j = 0; j < 16; ++j) {
    int h = (q << 4) + j;
    a += Qb[(size_t)h * NLQ + mq] * w2[h0 + h];
  }
  red[q][mq] = a;
  __syncthreads();
  if (q == 0)
    s2p[((size_t)blockIdx.y * NB + b) * NLQ + m0 + mq] =
        red[0][mq] + red[1][mq] + red[2][mq] + red[3][mq];
}

// combine 4 h-slice partials -> s1, s2
__global__ __launch_bounds__(256) void k_sfin(const float* __restrict__ s1p,
                                              const float* __restrict__ s2p,
                                              float* __restrict__ s1,
                                              float* __restrict__ s2) {
  int i = blockIdx.x * 256 + threadIdx.x;
  const int N1 = NB * NLC, N2 = NB * NLQ;
  if (i < N1) {
    s1[i] = s1p[i] + s1p[N1 + i] + s1p[2 * N1 + i] + s1p[3 * N1 + i];
  } else {
    int j = i - N1;
    s2[j] = s2p[j] + s2p[N2 + j] + s2p[2 * N2 + j] + s2p[3 * N2 + j];
  }
}

// ---------------- prep: plain f32 -> bf16 copies ----------------
__global__ __launch_bounds__(256) void k_prep_bf16(const float* __restrict__ X,
                                                   short* __restrict__ Y) {
  size_t i = ((size_t)blockIdx.x * 256 + threadIdx.x) * 8;
  float4 v0 = *(const float4*)&X[i];
  float4 v1 = *(const float4*)&X[i + 4];
  *(short8*)&Y[i] = cvt8(v0, v1);
}

// ------- S = Ct_lh @ Qtw3^T + s1 + s2  (M=l, N=m, K=h); 2-phase dbuf -------
__global__ __launch_bounds__(256) void k_sgemm(
    const short* __restrict__ Ct_lh, const short* __restrict__ Qtw3,
    const float* __restrict__ s1, const float* __restrict__ s2,
    float* __restrict__ S) {
  __shared__ short As[2][4096], Bs[2][4096];
  int b = blockIdx.z, l0 = blockIdx.y << 7, m0 = blockIdx.x << 7;
  GEMM_IDS
  const short* Ag = Ct_lh + ((size_t)b * NLC + l0) * NH;
  const short* Bg = Qtw3 + ((size_t)b * NLQ + m0) * NH;
  f32x4 acc[4][4] = {};
  stage_g(Ag, NH, As[0], t);
  stage_g(Bg, NH, Bs[0], t);
  __syncthreads();
  int cur = 0;
  for (int kn = 32; kn <= NH; kn += 32) {
    if (kn < NH) {
      stage_g(Ag + kn, NH, As[cur ^ 1], t);
      stage_g(Bg + kn, NH, Bs[cur ^ 1], t);
    }
    MFMA_STEP(As[cur], Bs[cur])
    __syncthreads();
    cur ^= 1;
  }
#pragma unroll
  for (int mi = 0; mi < 4; ++mi)
#pragma unroll
    for (int ni = 0; ni < 4; ++ni)
#pragma unroll
      for (int r = 0; r < 4; ++r) {
        int l = l0 + wr + mi * 16 + g * 4 + r;
        int m = m0 + wc + ni * 16 + ln;
        S[((size_t)b * NLC + l) * NLQ + m] =
            acc[mi][ni][r] + s1[b * NLC + l] + s2[b * NLQ + m];
      }
}

// per-column (over l) masked max & sum-exp partials, one 64-row chunk per block.
__global__ __launch_bounds__(256) void k_colpart(const float* __restrict__ S,
                                                 const int* __restrict__ cmask,
                                                 float* __restrict__ pmax,
                                                 float* __restrict__ psum) {
  int idx = blockIdx.x;  // ((b*4 + mb)*LCHUNK + chunk)
  int chunk = idx & (LCHUNK - 1);
  int mb = (idx >> 4) & 3;
  int b = idx >> 6;
  int m0 = mb << 6;
  int tx = threadIdx.x & 63, ty = threadIdx.x >> 6;
  const float* Sb = S + (size_t)b * NLC * NLQ + (size_t)(chunk * 64) * NLQ;
  const int* cm = cmask + b * NLC + chunk * 64;
  float mx = -INFINITY, sm = 0.f;
#pragma unroll 4
  for (int l = ty; l < 64; l += 4) {
    float x = Sb[(size_t)l * NLQ + m0 + tx] + (cm[l] ? 0.f : NEGV);
    float nmx = fmaxf(mx, x);
    sm = sm * expf(mx - nmx) + expf(x - nmx);
    mx = nmx;
  }
  __shared__ float smx[4][64], ssm[4][64];
  smx[ty][tx] = mx;
  ssm[ty][tx] = sm;
  __syncthreads();
  if (ty == 0) {
#pragma unroll
    for (int r = 1; r < 4; ++r) {
      float m2 = smx[r][tx], s2 = ssm[r][tx];
      float nm = fmaxf(mx, m2);
      sm = sm * expf(mx - nm) + s2 * expf(m2 - nm);
      mx = nm;
    }
    int m = (b << 8) + m0 + tx;  // global column id
    pmax[(size_t)m * LCHUNK + chunk] = mx;
    psum[(size_t)m * LCHUNK + chunk] = sm;
  }
}

// combine LCHUNK partials per column -> cmax, cinv. One thread per column.
__global__ __launch_bounds__(256) void k_colfin(const float* __restrict__ pmax,
                                                const float* __restrict__ psum,
                                                float* __restrict__ cmax,
                                                float* __restrict__ cinv) {
  int m = blockIdx.x * 256 + threadIdx.x;  // [0, NB*NLQ)
  const float* pm = pmax + (size_t)m * LCHUNK;
  const float* ps = psum + (size_t)m * LCHUNK;
  float mx = pm[0], sm = ps[0];
#pragma unroll
  for (int c = 1; c < LCHUNK; ++c) {
    float m2 = pm[c], s2 = ps[c];
    float nm = fmaxf(mx, m2);
    sm = sm * expf(mx - nm) + s2 * expf(m2 - nm);
    mx = nm;
  }
  cmax[m] = mx;
  cinv[m] = 1.0f / sm;
}

// ---- row+col softmax, IN PLACE: each 1KB f32 S row slot is replaced by
// bf16 P_row (bytes 0..511) and bf16 P_col (bytes 512..1023).
__global__ __launch_bounds__(256) void k_rowsoft(float* __restrict__ S,
                                                 const int* __restrict__ qmask,
                                                 const int* __restrict__ cmask,
                                                 const float* __restrict__ cmax,
                                                 const float* __restrict__ cinv) {
  int wave = threadIdx.x >> 6, lane = threadIdx.x & 63;
  int idx = (blockIdx.x << 2) + wave;  // row id in [0, NB*NLC)
  int b = idx >> 10;
  float* row = S + (size_t)idx * NLQ;
  const int* qm = qmask + b * NLQ;
  int m4 = lane << 2;
  float4 v = *(const float4*)&row[m4];
  int4 q = *(const int4*)&qm[m4];
  float x0 = v.x + (q.x ? 0.f : NEGV);
  float x1 = v.y + (q.y ? 0.f : NEGV);
  float x2 = v.z + (q.z ? 0.f : NEGV);
  float x3 = v.w + (q.w ? 0.f : NEGV);
  float mx = fmaxf(fmaxf(x0, x1), fmaxf(x2, x3));
#pragma unroll
  for (int off = 32; off > 0; off >>= 1) mx = fmaxf(mx, __shfl_xor(mx, off));
  float p0 = expf(x0 - mx), p1 = expf(x1 - mx);
  float p2 = expf(x2 - mx), p3 = expf(x3 - mx);
  float sm = p0 + p1 + p2 + p3;
#pragma unroll
  for (int off = 32; off > 0; off >>= 1) sm += __shfl_xor(sm, off);
  float iv = 1.0f / sm;
  short4 o;
  o.x = bf16_of(p0 * iv);
  o.y = bf16_of(p1 * iv);
  o.z = bf16_of(p2 * iv);
  o.w = bf16_of(p3 * iv);
  // col-softmax values for this row (normalized over l via cmax/cinv)
  float cmf = (float)cmask[idx];
  float4 cm4 = *(const float4*)&cmax[(b << 8) + m4];
  float4 ci4 = *(const float4*)&cinv[(b << 8) + m4];
  short4 oc;
  oc.x = bf16_of(expf(v.x - cm4.x) * ci4.x * cmf);
  oc.y = bf16_of(expf(v.y - cm4.y) * ci4.y * cmf);
  oc.z = bf16_of(expf(v.z - cm4.z) * ci4.z * cmf);
  oc.w = bf16_of(expf(v.w - cm4.w) * ci4.w * cmf);
  *(short4*)((short*)row + m4) = o;
  *(short4*)((short*)row + 256 + m4) = oc;
}

// ------ Tp[ks][b][h][m] = sum_{l in chunk ks} C[h][l] * P_col[l][m] ------
// split-K partials (f32); M=h, N=m, K=l chunk of 256. B is bf16 passthrough.
__global__ __launch_bounds__(256) void k_tgemm(const float* __restrict__ C,
                                               const short* __restrict__ PcolS,
                                               float* __restrict__ Tp) {
  __shared__ short As[4096], Bs[4096];
  int b = blockIdx.z;
  int ks = blockIdx.y;
  int h0 = (blockIdx.x & 1) << 7;
  int m0 = (blockIdx.x >> 1) << 7;
  GEMM_IDS
  const float* Cb = C + ((size_t)b * NH + h0) * NLC;
  const short* Pb = PcolS + (size_t)b * NLC * 512 + 256 + m0;
  f32x4 acc[4][4] = {};
  int kbeg = ks * (NLC / KSPLIT), kend = kbeg + NLC / KSPLIT;
  int ca = lane & 3;
  int lloc = t >> 3, g2 = lloc >> 3, kin = lloc & 7;
  int mbase = (t & 7) << 4;
  for (int k0 = kbeg; k0 < kend; k0 += 32) {
    __syncthreads();
    {  // A: reg-convert from f32 C (rows h, K=l minor)
#pragma unroll
      for (int i = 0; i < 2; ++i) {
        int seg = w + i * 4, r = seg * 16 + (lane >> 2);
        const float* src = &Cb[(size_t)r * NLC + k0 + ca * 8];
        float4 v0 = *(const float4*)src;
        float4 v1 = *(const float4*)(src + 4);
        lds_w8(As, r, ca, cvt8(v0, v1));
      }
    }
    {  // B: bf16 P_col passthrough, transposed into swizzled LDS
      const short* srow = Pb + (size_t)(k0 + lloc) * 512;
      short8 x0 = *(const short8*)&srow[mbase];
      short8 x1 = *(const short8*)&srow[mbase + 8];
#pragma unroll
      for (int j = 0; j < 8; ++j) {
        int R = mbase + j;
        int byteoff =
            (R << 6) + (((g2 ^ ((R >> 1) & 3)) & 3) << 4) + (kin << 1);
        *(short*)((char*)Bs + byteoff) = x0[j];
      }
#pragma unroll
      for (int j = 0; j < 8; ++j) {
        int R = mbase + 8 + j;
        int byteoff =
            (R << 6) + (((g2 ^ ((R >> 1) & 3)) & 3) << 4) + (kin << 1);
        *(short*)((char*)Bs + byteoff) = x1[j];
      }
    }
    __syncthreads();
    MFMA_STEP(As, Bs)
  }
  float* dst = Tp + ((size_t)ks * NB + b) * NH * NLQ;
#pragma unroll
  for (int mi = 0; mi < 4; ++mi)
#pragma unroll
    for (int ni = 0; ni < 4; ++ni)
#pragma unroll
      for (int r = 0; r < 4; ++r) {
        int h = h0 + wr + mi * 16 + g * 4 + r;
        int m = m0 + wc + ni * 16 + ln;
        dst[(size_t)h * NLQ + m] = acc[mi][ni][r];
      }
}

// reduce KSPLIT partials -> bf16 Tt[b][h][m]
__global__ __launch_bounds__(256) void k_tfin(const float* __restrict__ Tp,
                                              short* __restrict__ Tt) {
  size_t i = ((size_t)blockIdx.x * 256 + threadIdx.x) * 4;
  const size_t stride = (size_t)NB * NH * NLQ;
  float4 s = *(const float4*)&Tp[i];
#pragma unroll
  for (int ks = 1; ks < KSPLIT; ++ks) {
    float4 v = *(const float4*)&Tp[i + ks * stride];
    s.x += v.x; s.y += v.y; s.z += v.z; s.w += v.w;
  }
  short4 o;
  o.x = bf16_of(s.x);
  o.y = bf16_of(s.y);
  o.z = bf16_of(s.z);
  o.w = bf16_of(s.w);
  *(short4*)&Tt[i] = o;
}

// ---- [A | Ct*Bv][l][h] = f(sum_m P_row[l][m] * X[h][m]); 2-phase dbuf ----
__global__ __launch_bounds__(256) void k_abgemm(
    const short* __restrict__ Prow, const short* __restrict__ Qb_hm,
    const short* __restrict__ Tt, const short* __restrict__ Ct_lh,
    short* __restrict__ A_lh, short* __restrict__ CtBv_lh) {
  __shared__ short As[2][4096], Bs[2][4096];
  int b = blockIdx.z, l0 = blockIdx.y << 7, nb = blockIdx.x;
  GEMM_IDS
  const short* Ag = Prow + ((size_t)b * NLC + l0) * 512;
  const short* Bbase = (nb < 2)
                           ? Qb_hm + ((size_t)b * NH + nb * 128) * NLQ
                           : Tt + ((size_t)b * NH + (nb - 2) * 128) * NLQ;
  f32x4 acc[4][4] = {};
  stage_g(Ag, 512, As[0], t);
  stage_g(Bbase, NLQ, Bs[0], t);
  __syncthreads();
  int cur = 0;
  for (int kn = 32; kn <= NLQ; kn += 32) {
    if (kn < NLQ) {
      stage_g(Ag + kn, 512, As[cur ^ 1], t);
      stage_g(Bbase + kn, NLQ, Bs[cur ^ 1], t);
    }
    MFMA_STEP(As[cur], Bs[cur])
    __syncthreads();
    cur ^= 1;
  }
  int hbase = (nb & 1) << 7;
  if (nb < 2) {
#pragma unroll
    for (int mi = 0; mi < 4; ++mi)
#pragma unroll
      for (int ni = 0; ni < 4; ++ni)
#pragma unroll
        for (int r = 0; r < 4; ++r) {
          int l = l0 + wr + mi * 16 + g * 4 + r;
          int h = hbase + wc + ni * 16 + ln;
          A_lh[((size_t)b * NLC + l) * NH + h] = bf16_of(acc[mi][ni][r]);
        }
  } else {
#pragma unroll
    for (int mi = 0; mi < 4; ++mi)
#pragma unroll
      for (int ni = 0; ni < 4; ++ni)
#pragma unroll
        for (int r = 0; r < 4; ++r) {
          int l = l0 + wr + mi * 16 + g * 4 + r;
          int h = hbase + wc + ni * 16 + ln;
          size_t off = ((size_t)b * NLC + l) * NH + h;
          CtBv_lh[off] = bf16_of(f_of(Ct_lh[off]) * acc[mi][ni][r]);
        }
  }
}

// -------- out[h][l] = relu(b + sum_f W[h][f]*cat[l][f]); 2-phase dbuf --------
// cat regions along f: [Ct | A | Ct*A | Ct*Bv]; Wb is bf16 W_res.
__global__ __launch_bounds__(256) void k_out(
    const short* __restrict__ Wb, const short* __restrict__ Ct_lh,
    const short* __restrict__ A_lh, const short* __restrict__ CtBv_lh,
    const float* __restrict__ br, float* __restrict__ out) {
  __shared__ short As[2][4096], Bs[2][4096];
  int b = blockIdx.z, h0 = blockIdx.y << 7, l0 = blockIdx.x << 7;
  GEMM_IDS
  const short* Wg = Wb + (size_t)h0 * (4 * NH);
  size_t boff = ((size_t)b * NLC + l0) * NH;
  f32x4 acc[4][4] = {};
  stage_g(Wg, 4 * NH, As[0], t);
  stage_g(Ct_lh + boff, NH, Bs[0], t);  // tile 0 is region 0 (Ct)
  __syncthreads();
  int cur = 0;
  for (int kn = 32; kn <= 4 * NH; kn += 32) {
    bool has = kn < 4 * NH;
    int regn = kn >> 8, kon = kn & 255;
    short8 x1[2], x2[2];
    int ca = lane & 3;
    if (has) {
      stage_g(Wg + kn, 4 * NH, As[cur ^ 1], t);
      if (regn != 2) {
        const short* base = (regn == 0) ? Ct_lh : (regn == 1) ? A_lh : CtBv_lh;
        stage_g(base + boff + kon, NH, Bs[cur ^ 1], t);
      } else {
#pragma unroll
        for (int i = 0; i < 2; ++i) {
          int seg = w + i * 4, r = seg * 16 + (lane >> 2);
          size_t off = boff + (size_t)r * NH + kon + ca * 8;
          x1[i] = *(const short8*)&Ct_lh[off];
          x2[i] = *(const short8*)&A_lh[off];
        }
      }
    }
    MFMA_STEP(As[cur], Bs[cur])
    if (has && regn == 2) {
#pragma unroll
      for (int i = 0; i < 2; ++i) {
        int seg = w + i * 4, r = seg * 16 + (lane >> 2);
        short8 o;
#pragma unroll
        for (int j = 0; j < 8; ++j)
          o[j] = bf16_of(f_of(x1[i][j]) * f_of(x2[i][j]));
        lds_w8(Bs[cur ^ 1], r, ca, o);
      }
    }
    __syncthreads();
    cur ^= 1;
  }
#pragma unroll
  for (int mi = 0; mi < 4; ++mi)
#pragma unroll
    for (int ni = 0; ni < 4; ++ni) {
      int h = h0 + wr + mi * 16 + g * 4;
      int l = l0 + wc + ni * 16 + ln;
#pragma unroll
      for (int r = 0; r < 4; ++r) {
        float bias = br[h + r];
        out[((size_t)b * NH + h + r) * NLC + l] =
            fmaxf(acc[mi][ni][r] + bias, 0.f);
      }
    }
}

extern "C" void kernel_launch(void* const* d_in, const int* in_sizes, int n_in,
                              void* d_out, int out_size, void* d_ws,
                              size_t ws_size, hipStream_t stream) {
  (void)in_sizes;
  (void)n_in;
  (void)out_size;
  (void)ws_size;
  const float* C = (const float*)d_in[0];
  const float* Q = (const float*)d_in[1];
  const int* cmask = (const int*)d_in[2];
  const int* qmask = (const int*)d_in[3];
  const float* w = (const float*)d_in[4];
  const float* W = (const float*)d_in[5];
  const float* br = (const float*)d_in[6];
  float* out = (float*)d_out;

  char* p = (char*)d_ws;
  float* S = (float*)p;       p += (size_t)NB * NLC * NLQ * 4;   // 33.6 MB
  short* Ct_lh = (short*)p;   p += (size_t)NB * NLC * NH * 2;    // 16.8 MB
  short* A_lh = (short*)p;    p += (size_t)NB * NLC * NH * 2;    // 16.8 MB
  short* CtBv_lh = (short*)p; p += (size_t)NB * NLC * NH * 2;    // 16.8 MB
  short* Tt = (short*)p;      p += (size_t)NB * NH * NLQ * 2;    // 4.2 MB
  short* Qtw3 = (short*)p;    p += (size_t)NB * NLQ * NH * 2;    // 4.2 MB
  short* Qb_hm = (short*)p;   p += (size_t)NB * NH * NLQ * 2;    // 4.2 MB
  short* Wb = (short*)p;      p += (size_t)NH * 4 * NH * 2;      // 0.5 MB
  float* s1 = (float*)p;      p += (size_t)NB * NLC * 4;
  float* s2 = (float*)p;      p += (size_t)NB * NLQ * 4;
  float* cmax = (float*)p;    p += (size_t)NB * NLQ * 4;
  float* cinv = (float*)p;    p += (size_t)NB * NLQ * 4;
  float* pmax = (float*)p;    p += (size_t)NB * NLQ * LCHUNK * 4;
  float* psum = (float*)p;    p += (size_t)NB * NLQ * LCHUNK * 4;
  float* s1p = (float*)p;     p += (size_t)4 * NB * NLC * 4;     // 0.5 MB
  float* s2p = (float*)p;     p += (size_t)4 * NB * NLQ * 4;     // 0.13 MB
  // tgemm split-K partials: reuse A_lh+CtBv_lh (33.6 MB, dead until abgemm).
  float* Tp = (float*)A_lh;
  // in-place softmax: bf16 P_row at bytes 0..511, P_col at 512..1023 of each
  // 1KB S row (row stride 512 shorts).
  short* Prow = (short*)S;

  k_prep_c<<<dim3(NLC / 64, NH / 64, NB), dim3(256), 0, stream>>>(C, w, Ct_lh,
                                                                  s1p);
  k_prep_q<<<dim3(NLQ / 64, NH / 64, NB), dim3(256), 0, stream>>>(
      Q, w, Qtw3, Qb_hm, s2p);
  k_prep_bf16<<<dim3(NH * 4 * NH / 2048), dim3(256), 0, stream>>>(W, Wb);
  k_sfin<<<dim3((NB * NLC + NB * NLQ) / 256), dim3(256), 0, stream>>>(
      s1p, s2p, s1, s2);
  k_sgemm<<<dim3(NLQ / 128, NLC / 128, NB), dim3(256), 0, stream>>>(
      Ct_lh, Qtw3, s1, s2, S);
  k_colpart<<<dim3(NB * 4 * LCHUNK), dim3(256), 0, stream>>>(S, cmask, pmax,
                                                             psum);
  k_colfin<<<dim3(NB * NLQ / 256), dim3(256), 0, stream>>>(pmax, psum, cmax,
                                                           cinv);
  k_rowsoft<<<dim3(NB * NLC / 4), dim3(256), 0, stream>>>(S, qmask, cmask,
                                                          cmax, cinv);
  k_tgemm<<<dim3(4, KSPLIT, NB), dim3(256), 0, stream>>>(C, Prow, Tp);
  k_tfin<<<dim3(NB * NH * NLQ / 1024), dim3(256), 0, stream>>>(Tp, Tt);
  k_abgemm<<<dim3(4, NLC / 128, NB), dim3(256), 0, stream>>>(
      Prow, Qb_hm, Tt, Ct_lh, A_lh, CtBv_lh);
  k_out<<<dim3(NLC / 128, NH / 128, NB), dim3(256), 0, stream>>>(
      Wb, Ct_lh, A_lh, CtBv_lh, br, out);
}

// Round 9
// 145.999 us; speedup vs baseline: 1.2258x; 1.0535x over previous
//
#include <hip/hip_runtime.h>
#include <math.h>

#define NB 32
#define NH 256
#define NLC 1024
#define NLQ 256
#define NEGV (-1e30f)
#define TCH 8      // column-stats l-chunks (each 128 rows, = sgemm l-tile)
#define KSPLIT 4   // tgemm split-K factor

typedef short short8 __attribute__((ext_vector_type(8)));
typedef float f32x4 __attribute__((ext_vector_type(4)));

__device__ inline short bf16_of(float f) {
  union { float f; unsigned u; } v;
  v.f = f;
  unsigned r = (v.u + 0x7fffu + ((v.u >> 16) & 1u)) >> 16;
  return (short)r;
}
__device__ inline float f_of(short s) {
  union { unsigned u; float f; } v;
  v.u = ((unsigned)(unsigned short)s) << 16;
  return v.f;
}
__device__ inline short8 cvt8(float4 a, float4 b) {
  short8 o;
  o[0] = bf16_of(a.x); o[1] = bf16_of(a.y); o[2] = bf16_of(a.z); o[3] = bf16_of(a.w);
  o[4] = bf16_of(b.x); o[5] = bf16_of(b.y); o[6] = bf16_of(b.z); o[7] = bf16_of(b.w);
  return o;
}

// ---- swizzled 128x32 bf16 LDS tile helpers (row = 64B, slot ^= (row>>1)&3) ----
__device__ inline void lds_w8(short* lds, int r, int c, short8 v) {
  int byteoff = (r << 6) + (((c ^ ((r >> 1) & 3)) & 3) << 4);
  *(short8*)((char*)lds + byteoff) = v;
}
__device__ inline short8 lds_r8(const short* lds, int R, int g) {
  int byteoff = (R << 6) + (((g ^ ((R >> 1) & 3)) & 3) << 4);
  return *(const short8*)((const char*)lds + byteoff);
}
// global_load_lds staging of a 128x32 bf16 tile from K-minor src (ld elements).
// Source group pre-permuted per-lane so linear LDS bytes match swizzled reads.
__device__ inline void stage_g(const short* src, int ld, short* lds, int t) {
  int L = t & 63, w = t >> 6;
  int cp = (L & 3) ^ ((L >> 3) & 3);
#pragma unroll
  for (int i = 0; i < 2; ++i) {
    int seg = w + i * 4;
    const short* g = src + (size_t)(seg * 16 + (L >> 2)) * ld + cp * 8;
    __builtin_amdgcn_global_load_lds(
        (const __attribute__((address_space(1))) unsigned int*)g,
        (__attribute__((address_space(3))) unsigned int*)(lds + seg * 512), 16,
        0, 0);
  }
}

#define GEMM_IDS                                       \
  int t = threadIdx.x, lane = t & 63, w = t >> 6;      \
  int ln = lane & 15, g = lane >> 4;                   \
  int wr = (w >> 1) << 6, wc = (w & 1) << 6;           \
  (void)wr; (void)wc;

#define MFMA_STEP(AS, BS)                                                      \
  {                                                                            \
    short8 af[4], bfr[4];                                                      \
    _Pragma("unroll") for (int mi = 0; mi < 4; ++mi) af[mi] =                  \
        lds_r8(AS, wr + mi * 16 + ln, g);                                      \
    _Pragma("unroll") for (int ni = 0; ni < 4; ++ni) bfr[ni] =                 \
        lds_r8(BS, wc + ni * 16 + ln, g);                                      \
    _Pragma("unroll") for (int mi = 0; mi < 4; ++mi)                           \
        _Pragma("unroll") for (int ni = 0; ni < 4; ++ni) acc[mi][ni] =         \
            __builtin_amdgcn_mfma_f32_16x16x32_bf16(af[mi], bfr[ni],           \
                                                    acc[mi][ni], 0, 0, 0);     \
  }

// -- prep: Ct_lh[l][h] = bf16(C[h][l]); Cb_hl[h][l] = bf16(C); s1 partials --
__global__ __launch_bounds__(256) void k_prep_c(const float* __restrict__ C,
                                                const float* __restrict__ w,
                                                short* __restrict__ Ct_lh,
                                                short* __restrict__ Cb_hl,
                                                float* __restrict__ s1p) {
  __shared__ float Ts[64][65];
  __shared__ float red[4][64];
  int b = blockIdx.z, h0 = blockIdx.y << 6, l0 = blockIdx.x << 6;
  int t = threadIdx.x;
  int hr = t >> 4, lc = (t & 15) << 2;
  const float* Cb = C + ((size_t)b * NH + h0) * NLC + l0;
#pragma unroll
  for (int i = 0; i < 4; ++i) {
    int h = hr + i * 16;
    float4 v = *(const float4*)&Cb[(size_t)h * NLC + lc];
    short4 cb;
    cb.x = bf16_of(v.x); cb.y = bf16_of(v.y);
    cb.z = bf16_of(v.z); cb.w = bf16_of(v.w);
    *(short4*)&Cb_hl[((size_t)b * NH + h0 + h) * NLC + l0 + lc] = cb;
    Ts[h][lc + 0] = v.x;
    Ts[h][lc + 1] = v.y;
    Ts[h][lc + 2] = v.z;
    Ts[h][lc + 3] = v.w;
  }
  __syncthreads();
  int lr = t >> 2, hc = (t & 3) << 4;
  short* dst = &Ct_lh[((size_t)b * NLC + l0 + lr) * NH + h0 + hc];
  short8 o0, o1;
#pragma unroll
  for (int j = 0; j < 8; ++j) o0[j] = bf16_of(Ts[hc + j][lr]);
#pragma unroll
  for (int j = 0; j < 8; ++j) o1[j] = bf16_of(Ts[hc + 8 + j][lr]);
  *(short8*)dst = o0;
  *(short8*)(dst + 8) = o1;
  // s1 partial: sum over this block's 64 h of C[h][l]*w1[h]
  int q = t >> 6, lq = t & 63;
  float a = 0.f;
#pragma unroll
  for (int j = 0; j < 16; ++j) a += Ts[(q << 4) + j][lq] * w[h0 + (q << 4) + j];
  red[q][lq] = a;
  __syncthreads();
  if (q == 0)
    s1p[((size_t)blockIdx.y * NB + b) * NLC + l0 + lq] =
        red[0][lq] + red[1][lq] + red[2][lq] + red[3][lq];
}

// ---- prep: Qtw3[m][h]=bf16(Q[h][m]*w3[h]); Qb_hm=bf16(Q); s2 partials ----
__global__ __launch_bounds__(256) void k_prep_q(const float* __restrict__ Q,
                                                const float* __restrict__ w,
                                                short* __restrict__ Qtw3,
                                                short* __restrict__ Qb_hm,
                                                float* __restrict__ s2p) {
  __shared__ float Ts[64][65];
  __shared__ float red[4][64];
  int b = blockIdx.z, h0 = blockIdx.y << 6, m0 = blockIdx.x << 6;
  int t = threadIdx.x;
  int hr = t >> 4, mc = (t & 15) << 2;
  const float* w3 = w + 2 * NH;
  const float* Qb = Q + ((size_t)b * NH + h0) * NLQ + m0;
#pragma unroll
  for (int i = 0; i < 4; ++i) {
    int h = hr + i * 16;
    float w3v = w3[h0 + h];
    float4 v = *(const float4*)&Qb[(size_t)h * NLQ + mc];
    short4 qb;
    qb.x = bf16_of(v.x); qb.y = bf16_of(v.y);
    qb.z = bf16_of(v.z); qb.w = bf16_of(v.w);
    *(short4*)&Qb_hm[((size_t)b * NH + h0 + h) * NLQ + m0 + mc] = qb;
    Ts[h][mc + 0] = v.x * w3v;
    Ts[h][mc + 1] = v.y * w3v;
    Ts[h][mc + 2] = v.z * w3v;
    Ts[h][mc + 3] = v.w * w3v;
  }
  __syncthreads();
  int mr = t >> 2, hc = (t & 3) << 4;
  short* dst = &Qtw3[((size_t)b * NLQ + m0 + mr) * NH + h0 + hc];
  short8 o0, o1;
#pragma unroll
  for (int j = 0; j < 8; ++j) o0[j] = bf16_of(Ts[hc + j][mr]);
#pragma unroll
  for (int j = 0; j < 8; ++j) o1[j] = bf16_of(Ts[hc + 8 + j][mr]);
  *(short8*)dst = o0;
  *(short8*)(dst + 8) = o1;
  // s2 partial over this block's 64 h (reload raw Q; L1-hot)
  int q = t >> 6, mq = t & 63;
  const float* w2 = w + NH;
  float a = 0.f;
#pragma unroll
  for (int j = 0; j < 16; ++j) {
    int h = (q << 4) + j;
    a += Qb[(size_t)h * NLQ + mq] * w2[h0 + h];
  }
  red[q][mq] = a;
  __syncthreads();
  if (q == 0)
    s2p[((size_t)blockIdx.y * NB + b) * NLQ + m0 + mq] =
        red[0][mq] + red[1][mq] + red[2][mq] + red[3][mq];
}

// combine 4 h-slice partials -> s1, s2
__global__ __launch_bounds__(256) void k_sfin(const float* __restrict__ s1p,
                                              const float* __restrict__ s2p,
                                              float* __restrict__ s1,
                                              float* __restrict__ s2) {
  int i = blockIdx.x * 256 + threadIdx.x;
  const int N1 = NB * NLC, N2 = NB * NLQ;
  if (i < N1) {
    s1[i] = s1p[i] + s1p[N1 + i] + s1p[2 * N1 + i] + s1p[3 * N1 + i];
  } else {
    int j = i - N1;
    s2[j] = s2p[j] + s2p[N2 + j] + s2p[2 * N2 + j] + s2p[3 * N2 + j];
  }
}

// ---------------- prep: plain f32 -> bf16 copies ----------------
__global__ __launch_bounds__(256) void k_prep_bf16(const float* __restrict__ X,
                                                   short* __restrict__ Y) {
  size_t i = ((size_t)blockIdx.x * 256 + threadIdx.x) * 8;
  float4 v0 = *(const float4*)&X[i];
  float4 v1 = *(const float4*)&X[i + 4];
  *(short8*)&Y[i] = cvt8(v0, v1);
}

// ------- S = Ct_lh @ Qtw3^T + s1 + s2  (M=l, N=m, K=h); 2-phase dbuf.
// Epilogue also emits column-softmax partials (masked max/sum-exp over this
// block's 128 l) straight from registers -> pmax/psum chunk = blockIdx.y.
__global__ __launch_bounds__(256) void k_sgemm(
    const short* __restrict__ Ct_lh, const short* __restrict__ Qtw3,
    const float* __restrict__ s1, const float* __restrict__ s2,
    const int* __restrict__ cmask, float* __restrict__ S,
    float* __restrict__ pmax, float* __restrict__ psum) {
  __shared__ short As[2][4096], Bs[2][4096];
  __shared__ float cmsh[128];
  __shared__ float sredm[4][4][16], sreds[4][4][16];
  int b = blockIdx.z, l0 = blockIdx.y << 7, m0 = blockIdx.x << 7;
  GEMM_IDS
  const short* Ag = Ct_lh + ((size_t)b * NLC + l0) * NH;
  const short* Bg = Qtw3 + ((size_t)b * NLQ + m0) * NH;
  f32x4 acc[4][4] = {};
  stage_g(Ag, NH, As[0], t);
  stage_g(Bg, NH, Bs[0], t);
  __syncthreads();
  int cur = 0;
  for (int kn = 32; kn <= NH; kn += 32) {
    if (kn < NH) {
      stage_g(Ag + kn, NH, As[cur ^ 1], t);
      stage_g(Bg + kn, NH, Bs[cur ^ 1], t);
    }
    MFMA_STEP(As[cur], Bs[cur])
    __syncthreads();
    cur ^= 1;
  }
  // ---- epilogue: S write + column partials from registers ----
  if (t < 128) cmsh[t] = cmask[b * NLC + l0 + t] ? 0.f : NEGV;
  __syncthreads();
  float s1r[16], ncr[16];
#pragma unroll
  for (int mi = 0; mi < 4; ++mi)
#pragma unroll
    for (int r = 0; r < 4; ++r) {
      int lloc = wr + mi * 16 + g * 4 + r;
      s1r[mi * 4 + r] = s1[b * NLC + l0 + lloc];
      ncr[mi * 4 + r] = cmsh[lloc];
    }
  float s2v[4], mxc[4], smc[4];
#pragma unroll
  for (int ni = 0; ni < 4; ++ni) {
    s2v[ni] = s2[b * NLQ + m0 + wc + ni * 16 + ln];
    mxc[ni] = -INFINITY;
    smc[ni] = 0.f;
  }
#pragma unroll
  for (int ni = 0; ni < 4; ++ni)
#pragma unroll
    for (int mi = 0; mi < 4; ++mi)
#pragma unroll
      for (int r = 0; r < 4; ++r)
        mxc[ni] = fmaxf(mxc[ni],
                        acc[mi][ni][r] + s1r[mi * 4 + r] + s2v[ni] +
                            ncr[mi * 4 + r]);
#pragma unroll
  for (int ni = 0; ni < 4; ++ni) {
    int m = m0 + wc + ni * 16 + ln;
#pragma unroll
    for (int mi = 0; mi < 4; ++mi)
#pragma unroll
      for (int r = 0; r < 4; ++r) {
        int l = l0 + wr + mi * 16 + g * 4 + r;
        float sv = acc[mi][ni][r] + s1r[mi * 4 + r] + s2v[ni];
        S[((size_t)b * NLC + l) * NLQ + m] = sv;
        smc[ni] += expf(sv + ncr[mi * 4 + r] - mxc[ni]);
      }
  }
  // butterfly across the 4 lane-groups (same ln, different g)
#pragma unroll
  for (int off = 16; off <= 32; off <<= 1)
#pragma unroll
    for (int ni = 0; ni < 4; ++ni) {
      float m2 = __shfl_xor(mxc[ni], off);
      float s2x = __shfl_xor(smc[ni], off);
      float nm = fmaxf(mxc[ni], m2);
      smc[ni] = smc[ni] * expf(mxc[ni] - nm) + s2x * expf(m2 - nm);
      mxc[ni] = nm;
    }
  if (lane < 16) {
#pragma unroll
    for (int ni = 0; ni < 4; ++ni) {
      sredm[w][ni][lane] = mxc[ni];
      sreds[w][ni][lane] = smc[ni];
    }
  }
  __syncthreads();
  if (t < 128) {
    int wcsel = t >> 6, nii = (t >> 4) & 3, lnn = t & 15;
    float mA = sredm[wcsel][nii][lnn], sA = sreds[wcsel][nii][lnn];
    float mB = sredm[wcsel + 2][nii][lnn], sB = sreds[wcsel + 2][nii][lnn];
    float nm = fmaxf(mA, mB);
    float sm = sA * expf(mA - nm) + sB * expf(mB - nm);
    int m = m0 + (wcsel << 6) + nii * 16 + lnn;
    size_t base = ((size_t)b * NLQ + m) * TCH + blockIdx.y;
    pmax[base] = nm;
    psum[base] = sm;
  }
}

// combine TCH partials per column -> cmax, cinv. One thread per column.
__global__ __launch_bounds__(256) void k_colfin(const float* __restrict__ pmax,
                                                const float* __restrict__ psum,
                                                float* __restrict__ cmax,
                                                float* __restrict__ cinv) {
  int m = blockIdx.x * 256 + threadIdx.x;  // [0, NB*NLQ)
  const float* pm = pmax + (size_t)m * TCH;
  const float* ps = psum + (size_t)m * TCH;
  float mx = pm[0], sm = ps[0];
#pragma unroll
  for (int c = 1; c < TCH; ++c) {
    float m2 = pm[c], s2 = ps[c];
    float nm = fmaxf(mx, m2);
    sm = sm * expf(mx - nm) + s2 * expf(m2 - nm);
    mx = nm;
  }
  cmax[m] = mx;
  cinv[m] = 1.0f / sm;
}

// ---- row+col softmax, IN PLACE: each 1KB f32 S row slot is replaced by
// bf16 P_row (bytes 0..511) and bf16 P_col (bytes 512..1023).
__global__ __launch_bounds__(256) void k_rowsoft(float* __restrict__ S,
                                                 const int* __restrict__ qmask,
                                                 const int* __restrict__ cmask,
                                                 const float* __restrict__ cmax,
                                                 const float* __restrict__ cinv) {
  int wave = threadIdx.x >> 6, lane = threadIdx.x & 63;
  int idx = (blockIdx.x << 2) + wave;  // row id in [0, NB*NLC)
  int b = idx >> 10;
  float* row = S + (size_t)idx * NLQ;
  const int* qm = qmask + b * NLQ;
  int m4 = lane << 2;
  float4 v = *(const float4*)&row[m4];
  int4 q = *(const int4*)&qm[m4];
  float x0 = v.x + (q.x ? 0.f : NEGV);
  float x1 = v.y + (q.y ? 0.f : NEGV);
  float x2 = v.z + (q.z ? 0.f : NEGV);
  float x3 = v.w + (q.w ? 0.f : NEGV);
  float mx = fmaxf(fmaxf(x0, x1), fmaxf(x2, x3));
#pragma unroll
  for (int off = 32; off > 0; off >>= 1) mx = fmaxf(mx, __shfl_xor(mx, off));
  float p0 = expf(x0 - mx), p1 = expf(x1 - mx);
  float p2 = expf(x2 - mx), p3 = expf(x3 - mx);
  float sm = p0 + p1 + p2 + p3;
#pragma unroll
  for (int off = 32; off > 0; off >>= 1) sm += __shfl_xor(sm, off);
  float iv = 1.0f / sm;
  short4 o;
  o.x = bf16_of(p0 * iv);
  o.y = bf16_of(p1 * iv);
  o.z = bf16_of(p2 * iv);
  o.w = bf16_of(p3 * iv);
  // col-softmax values for this row (normalized over l via cmax/cinv)
  float cmf = (float)cmask[idx];
  float4 cm4 = *(const float4*)&cmax[(b << 8) + m4];
  float4 ci4 = *(const float4*)&cinv[(b << 8) + m4];
  short4 oc;
  oc.x = bf16_of(expf(v.x - cm4.x) * ci4.x * cmf);
  oc.y = bf16_of(expf(v.y - cm4.y) * ci4.y * cmf);
  oc.z = bf16_of(expf(v.z - cm4.z) * ci4.z * cmf);
  oc.w = bf16_of(expf(v.w - cm4.w) * ci4.w * cmf);
  *(short4*)((short*)row + m4) = o;
  *(short4*)((short*)row + 256 + m4) = oc;
}

// ------ Tp[ks][b][h][m] = sum_{l in chunk ks} C[h][l] * P_col[l][m] ------
// split-K partials (f32); M=h, N=m, K=l chunk of 256.
// A: bf16 Cb_hl via stage_g (DMA). B: bf16 P_col transposed scatter.
__global__ __launch_bounds__(256) void k_tgemm(const short* __restrict__ Cb_hl,
                                               const short* __restrict__ PcolS,
                                               float* __restrict__ Tp) {
  __shared__ short As[4096], Bs[4096];
  int b = blockIdx.z;
  int ks = blockIdx.y;
  int h0 = (blockIdx.x & 1) << 7;
  int m0 = (blockIdx.x >> 1) << 7;
  GEMM_IDS
  const short* Ag = Cb_hl + ((size_t)b * NH + h0) * NLC;
  const short* Pb = PcolS + (size_t)b * NLC * 512 + 256 + m0;
  f32x4 acc[4][4] = {};
  int kbeg = ks * (NLC / KSPLIT), kend = kbeg + NLC / KSPLIT;
  int lloc = t >> 3, g2 = lloc >> 3, kin = lloc & 7;
  int mbase = (t & 7) << 4;
  for (int k0 = kbeg; k0 < kend; k0 += 32) {
    __syncthreads();
    stage_g(Ag + k0, NLC, As, t);
    {  // B: bf16 P_col passthrough, transposed into swizzled LDS
      const short* srow = Pb + (size_t)(k0 + lloc) * 512;
      short8 x0 = *(const short8*)&srow[mbase];
      short8 x1 = *(const short8*)&srow[mbase + 8];
#pragma unroll
      for (int j = 0; j < 8; ++j) {
        int R = mbase + j;
        int byteoff =
            (R << 6) + (((g2 ^ ((R >> 1) & 3)) & 3) << 4) + (kin << 1);
        *(short*)((char*)Bs + byteoff) = x0[j];
      }
#pragma unroll
      for (int j = 0; j < 8; ++j) {
        int R = mbase + 8 + j;
        int byteoff =
            (R << 6) + (((g2 ^ ((R >> 1) & 3)) & 3) << 4) + (kin << 1);
        *(short*)((char*)Bs + byteoff) = x1[j];
      }
    }
    __syncthreads();
    MFMA_STEP(As, Bs)
  }
  float* dst = Tp + ((size_t)ks * NB + b) * NH * NLQ;
#pragma unroll
  for (int mi = 0; mi < 4; ++mi)
#pragma unroll
    for (int ni = 0; ni < 4; ++ni)
#pragma unroll
      for (int r = 0; r < 4; ++r) {
        int h = h0 + wr + mi * 16 + g * 4 + r;
        int m = m0 + wc + ni * 16 + ln;
        dst[(size_t)h * NLQ + m] = acc[mi][ni][r];
      }
}

// reduce KSPLIT partials -> bf16 Tt[b][h][m]
__global__ __launch_bounds__(256) void k_tfin(const float* __restrict__ Tp,
                                              short* __restrict__ Tt) {
  size_t i = ((size_t)blockIdx.x * 256 + threadIdx.x) * 4;
  const size_t stride = (size_t)NB * NH * NLQ;
  float4 s = *(const float4*)&Tp[i];
#pragma unroll
  for (int ks = 1; ks < KSPLIT; ++ks) {
    float4 v = *(const float4*)&Tp[i + ks * stride];
    s.x += v.x; s.y += v.y; s.z += v.z; s.w += v.w;
  }
  short4 o;
  o.x = bf16_of(s.x);
  o.y = bf16_of(s.y);
  o.z = bf16_of(s.z);
  o.w = bf16_of(s.w);
  *(short4*)&Tt[i] = o;
}

// ---- [A | Ct*Bv][l][h] = f(sum_m P_row[l][m] * X[h][m]); 2-phase dbuf ----
__global__ __launch_bounds__(256) void k_abgemm(
    const short* __restrict__ Prow, const short* __restrict__ Qb_hm,
    const short* __restrict__ Tt, const short* __restrict__ Ct_lh,
    short* __restrict__ A_lh, short* __restrict__ CtBv_lh) {
  __shared__ short As[2][4096], Bs[2][4096];
  int b = blockIdx.z, l0 = blockIdx.y << 7, nb = blockIdx.x;
  GEMM_IDS
  const short* Ag = Prow + ((size_t)b * NLC + l0) * 512;
  const short* Bbase = (nb < 2)
                           ? Qb_hm + ((size_t)b * NH + nb * 128) * NLQ
                           : Tt + ((size_t)b * NH + (nb - 2) * 128) * NLQ;
  f32x4 acc[4][4] = {};
  stage_g(Ag, 512, As[0], t);
  stage_g(Bbase, NLQ, Bs[0], t);
  __syncthreads();
  int cur = 0;
  for (int kn = 32; kn <= NLQ; kn += 32) {
    if (kn < NLQ) {
      stage_g(Ag + kn, 512, As[cur ^ 1], t);
      stage_g(Bbase + kn, NLQ, Bs[cur ^ 1], t);
    }
    MFMA_STEP(As[cur], Bs[cur])
    __syncthreads();
    cur ^= 1;
  }
  int hbase = (nb & 1) << 7;
  if (nb < 2) {
#pragma unroll
    for (int mi = 0; mi < 4; ++mi)
#pragma unroll
      for (int ni = 0; ni < 4; ++ni)
#pragma unroll
        for (int r = 0; r < 4; ++r) {
          int l = l0 + wr + mi * 16 + g * 4 + r;
          int h = hbase + wc + ni * 16 + ln;
          A_lh[((size_t)b * NLC + l) * NH + h] = bf16_of(acc[mi][ni][r]);
        }
  } else {
#pragma unroll
    for (int mi = 0; mi < 4; ++mi)
#pragma unroll
      for (int ni = 0; ni < 4; ++ni)
#pragma unroll
        for (int r = 0; r < 4; ++r) {
          int l = l0 + wr + mi * 16 + g * 4 + r;
          int h = hbase + wc + ni * 16 + ln;
          size_t off = ((size_t)b * NLC + l) * NH + h;
          CtBv_lh[off] = bf16_of(f_of(Ct_lh[off]) * acc[mi][ni][r]);
        }
  }
}

// -------- out[h][l] = relu(b + sum_f W[h][f]*cat[l][f]); 2-phase dbuf --------
// cat regions along f: [Ct | A | Ct*A | Ct*Bv]; Wb is bf16 W_res.
__global__ __launch_bounds__(256) void k_out(
    const short* __restrict__ Wb, const short* __restrict__ Ct_lh,
    const short* __restrict__ A_lh, const short* __restrict__ CtBv_lh,
    const float* __restrict__ br, float* __restrict__ out) {
  __shared__ short As[2][4096], Bs[2][4096];
  int b = blockIdx.z, h0 = blockIdx.y << 7, l0 = blockIdx.x << 7;
  GEMM_IDS
  const short* Wg = Wb + (size_t)h0 * (4 * NH);
  size_t boff = ((size_t)b * NLC + l0) * NH;
  f32x4 acc[4][4] = {};
  stage_g(Wg, 4 * NH, As[0], t);
  stage_g(Ct_lh + boff, NH, Bs[0], t);  // tile 0 is region 0 (Ct)
  __syncthreads();
  int cur = 0;
  for (int kn = 32; kn <= 4 * NH; kn += 32) {
    bool has = kn < 4 * NH;
    int regn = kn >> 8, kon = kn & 255;
    short8 x1[2], x2[2];
    int ca = lane & 3;
    if (has) {
      stage_g(Wg + kn, 4 * NH, As[cur ^ 1], t);
      if (regn != 2) {
        const short* base = (regn == 0) ? Ct_lh : (regn == 1) ? A_lh : CtBv_lh;
        stage_g(base + boff + kon, NH, Bs[cur ^ 1], t);
      } else {
#pragma unroll
        for (int i = 0; i < 2; ++i) {
          int seg = w + i * 4, r = seg * 16 + (lane >> 2);
          size_t off = boff + (size_t)r * NH + kon + ca * 8;
          x1[i] = *(const short8*)&Ct_lh[off];
          x2[i] = *(const short8*)&A_lh[off];
        }
      }
    }
    MFMA_STEP(As[cur], Bs[cur])
    if (has && regn == 2) {
#pragma unroll
      for (int i = 0; i < 2; ++i) {
        int seg = w + i * 4, r = seg * 16 + (lane >> 2);
        short8 o;
#pragma unroll
        for (int j = 0; j < 8; ++j)
          o[j] = bf16_of(f_of(x1[i][j]) * f_of(x2[i][j]));
        lds_w8(Bs[cur ^ 1], r, ca, o);
      }
    }
    __syncthreads();
    cur ^= 1;
  }
#pragma unroll
  for (int mi = 0; mi < 4; ++mi)
#pragma unroll
    for (int ni = 0; ni < 4; ++ni) {
      int h = h0 + wr + mi * 16 + g * 4;
      int l = l0 + wc + ni * 16 + ln;
#pragma unroll
      for (int r = 0; r < 4; ++r) {
        float bias = br[h + r];
        out[((size_t)b * NH + h + r) * NLC + l] =
            fmaxf(acc[mi][ni][r] + bias, 0.f);
      }
    }
}

extern "C" void kernel_launch(void* const* d_in, const int* in_sizes, int n_in,
                              void* d_out, int out_size, void* d_ws,
                              size_t ws_size, hipStream_t stream) {
  (void)in_sizes;
  (void)n_in;
  (void)out_size;
  (void)ws_size;
  const float* C = (const float*)d_in[0];
  const float* Q = (const float*)d_in[1];
  const int* cmask = (const int*)d_in[2];
  const int* qmask = (const int*)d_in[3];
  const float* w = (const float*)d_in[4];
  const float* W = (const float*)d_in[5];
  const float* br = (const float*)d_in[6];
  float* out = (float*)d_out;

  char* p = (char*)d_ws;
  float* S = (float*)p;       p += (size_t)NB * NLC * NLQ * 4;   // 33.6 MB
  short* Ct_lh = (short*)p;   p += (size_t)NB * NLC * NH * 2;    // 16.8 MB
  short* A_lh = (short*)p;    p += (size_t)NB * NLC * NH * 2;    // 16.8 MB
  short* CtBv_lh = (short*)p; p += (size_t)NB * NLC * NH * 2;    // 16.8 MB
  short* Cb_hl = (short*)p;   p += (size_t)NB * NH * NLC * 2;    // 16.8 MB
  short* Tt = (short*)p;      p += (size_t)NB * NH * NLQ * 2;    // 4.2 MB
  short* Qtw3 = (short*)p;    p += (size_t)NB * NLQ * NH * 2;    // 4.2 MB
  short* Qb_hm = (short*)p;   p += (size_t)NB * NH * NLQ * 2;    // 4.2 MB
  short* Wb = (short*)p;      p += (size_t)NH * 4 * NH * 2;      // 0.5 MB
  float* s1 = (float*)p;      p += (size_t)NB * NLC * 4;
  float* s2 = (float*)p;      p += (size_t)NB * NLQ * 4;
  float* cmax = (float*)p;    p += (size_t)NB * NLQ * 4;
  float* cinv = (float*)p;    p += (size_t)NB * NLQ * 4;
  float* pmax = (float*)p;    p += (size_t)NB * NLQ * TCH * 4;
  float* psum = (float*)p;    p += (size_t)NB * NLQ * TCH * 4;
  float* s1p = (float*)p;     p += (size_t)4 * NB * NLC * 4;     // 0.5 MB
  float* s2p = (float*)p;     p += (size_t)4 * NB * NLQ * 4;     // 0.13 MB
  // tgemm split-K partials: reuse A_lh+CtBv_lh (33.6 MB, dead until abgemm).
  float* Tp = (float*)A_lh;
  // in-place softmax: bf16 P_row at bytes 0..511, P_col at 512..1023 of each
  // 1KB S row (row stride 512 shorts).
  short* Prow = (short*)S;

  k_prep_c<<<dim3(NLC / 64, NH / 64, NB), dim3(256), 0, stream>>>(C, w, Ct_lh,
                                                                  Cb_hl, s1p);
  k_prep_q<<<dim3(NLQ / 64, NH / 64, NB), dim3(256), 0, stream>>>(
      Q, w, Qtw3, Qb_hm, s2p);
  k_prep_bf16<<<dim3(NH * 4 * NH / 2048), dim3(256), 0, stream>>>(W, Wb);
  k_sfin<<<dim3((NB * NLC + NB * NLQ) / 256), dim3(256), 0, stream>>>(
      s1p, s2p, s1, s2);
  k_sgemm<<<dim3(NLQ / 128, NLC / 128, NB), dim3(256), 0, stream>>>(
      Ct_lh, Qtw3, s1, s2, cmask, S, pmax, psum);
  k_colfin<<<dim3(NB * NLQ / 256), dim3(256), 0, stream>>>(pmax, psum, cmax,
                                                           cinv);
  k_rowsoft<<<dim3(NB * NLC / 4), dim3(256), 0, stream>>>(S, qmask, cmask,
                                                          cmax, cinv);
  k_tgemm<<<dim3(4, KSPLIT, NB), dim3(256), 0, stream>>>(Cb_hl, Prow, Tp);
  k_tfin<<<dim3(NB * NH * NLQ / 1024), dim3(256), 0, stream>>>(Tp, Tt);
  k_abgemm<<<dim3(4, NLC / 128, NB), dim3(256), 0, stream>>>(
      Prow, Qb_hm, Tt, Ct_lh, A_lh, CtBv_lh);
  k_out<<<dim3(NLC / 128, NH / 128, NB), dim3(256), 0, stream>>>(
      Wb, Ct_lh, A_lh, CtBv_lh, br, out);
}

// Round 10
// 143.721 us; speedup vs baseline: 1.2453x; 1.0158x over previous
//
#include <hip/hip_runtime.h>
#include <math.h>

#define NB 32
#define NH 256
#define NLC 1024
#define NLQ 256
#define NEGV (-1e30f)
#define TCH 8      // column-stats l-chunks (each 128 rows, = sgemm l-tile)
#define KSPLIT 4   // tgemm split-K factor

typedef short short8 __attribute__((ext_vector_type(8)));
typedef float f32x4 __attribute__((ext_vector_type(4)));

__device__ inline short bf16_of(float f) {
  union { float f; unsigned u; } v;
  v.f = f;
  unsigned r = (v.u + 0x7fffu + ((v.u >> 16) & 1u)) >> 16;
  return (short)r;
}
__device__ inline float f_of(short s) {
  union { unsigned u; float f; } v;
  v.u = ((unsigned)(unsigned short)s) << 16;
  return v.f;
}
__device__ inline short8 cvt8(float4 a, float4 b) {
  short8 o;
  o[0] = bf16_of(a.x); o[1] = bf16_of(a.y); o[2] = bf16_of(a.z); o[3] = bf16_of(a.w);
  o[4] = bf16_of(b.x); o[5] = bf16_of(b.y); o[6] = bf16_of(b.z); o[7] = bf16_of(b.w);
  return o;
}

// XCD-aware bijective block swizzle (T1): consecutive logical tiles land on
// the same XCD's L2 so operand-sharing neighbor blocks hit instead of miss.
// Requires nwg % 8 == 0 (all our GEMM grids are).
#define XCD_SWZ(GX, GY, GZ, bx, by, bz)                                 \
  int bx, by, bz;                                                       \
  {                                                                     \
    int _lin = blockIdx.x + (GX) * (blockIdx.y + (GY) * blockIdx.z);    \
    const int _nwg = (GX) * (GY) * (GZ);                                \
    _lin = (_lin & 7) * (_nwg >> 3) + (_lin >> 3);                      \
    bx = _lin % (GX);                                                   \
    by = (_lin / (GX)) % (GY);                                          \
    bz = _lin / ((GX) * (GY));                                          \
  }

// ---- swizzled 128x32 bf16 LDS tile helpers (row = 64B, slot ^= (row>>1)&3) ----
__device__ inline void lds_w8(short* lds, int r, int c, short8 v) {
  int byteoff = (r << 6) + (((c ^ ((r >> 1) & 3)) & 3) << 4);
  *(short8*)((char*)lds + byteoff) = v;
}
__device__ inline short8 lds_r8(const short* lds, int R, int g) {
  int byteoff = (R << 6) + (((g ^ ((R >> 1) & 3)) & 3) << 4);
  return *(const short8*)((const char*)lds + byteoff);
}
// global_load_lds staging of a 128x32 bf16 tile from K-minor src (ld elements).
// Source group pre-permuted per-lane so linear LDS bytes match swizzled reads.
__device__ inline void stage_g(const short* src, int ld, short* lds, int t) {
  int L = t & 63, w = t >> 6;
  int cp = (L & 3) ^ ((L >> 3) & 3);
#pragma unroll
  for (int i = 0; i < 2; ++i) {
    int seg = w + i * 4;
    const short* g = src + (size_t)(seg * 16 + (L >> 2)) * ld + cp * 8;
    __builtin_amdgcn_global_load_lds(
        (const __attribute__((address_space(1))) unsigned int*)g,
        (__attribute__((address_space(3))) unsigned int*)(lds + seg * 512), 16,
        0, 0);
  }
}

#define GEMM_IDS                                       \
  int t = threadIdx.x, lane = t & 63, w = t >> 6;      \
  int ln = lane & 15, g = lane >> 4;                   \
  int wr = (w >> 1) << 6, wc = (w & 1) << 6;           \
  (void)wr; (void)wc;

#define MFMA_STEP(AS, BS)                                                      \
  {                                                                            \
    short8 af[4], bfr[4];                                                      \
    _Pragma("unroll") for (int mi = 0; mi < 4; ++mi) af[mi] =                  \
        lds_r8(AS, wr + mi * 16 + ln, g);                                      \
    _Pragma("unroll") for (int ni = 0; ni < 4; ++ni) bfr[ni] =                 \
        lds_r8(BS, wc + ni * 16 + ln, g);                                      \
    _Pragma("unroll") for (int mi = 0; mi < 4; ++mi)                           \
        _Pragma("unroll") for (int ni = 0; ni < 4; ++ni) acc[mi][ni] =         \
            __builtin_amdgcn_mfma_f32_16x16x32_bf16(af[mi], bfr[ni],           \
                                                    acc[mi][ni], 0, 0, 0);     \
  }

// -- prep: Ct_lh[l][h] = bf16(C[h][l]); Cb_hl[h][l] = bf16(C); s1 partials --
__global__ __launch_bounds__(256) void k_prep_c(const float* __restrict__ C,
                                                const float* __restrict__ w,
                                                short* __restrict__ Ct_lh,
                                                short* __restrict__ Cb_hl,
                                                float* __restrict__ s1p) {
  __shared__ float Ts[64][65];
  __shared__ float red[4][64];
  int b = blockIdx.z, h0 = blockIdx.y << 6, l0 = blockIdx.x << 6;
  int t = threadIdx.x;
  int hr = t >> 4, lc = (t & 15) << 2;
  const float* Cb = C + ((size_t)b * NH + h0) * NLC + l0;
#pragma unroll
  for (int i = 0; i < 4; ++i) {
    int h = hr + i * 16;
    float4 v = *(const float4*)&Cb[(size_t)h * NLC + lc];
    short4 cb;
    cb.x = bf16_of(v.x); cb.y = bf16_of(v.y);
    cb.z = bf16_of(v.z); cb.w = bf16_of(v.w);
    *(short4*)&Cb_hl[((size_t)b * NH + h0 + h) * NLC + l0 + lc] = cb;
    Ts[h][lc + 0] = v.x;
    Ts[h][lc + 1] = v.y;
    Ts[h][lc + 2] = v.z;
    Ts[h][lc + 3] = v.w;
  }
  __syncthreads();
  int lr = t >> 2, hc = (t & 3) << 4;
  short* dst = &Ct_lh[((size_t)b * NLC + l0 + lr) * NH + h0 + hc];
  short8 o0, o1;
#pragma unroll
  for (int j = 0; j < 8; ++j) o0[j] = bf16_of(Ts[hc + j][lr]);
#pragma unroll
  for (int j = 0; j < 8; ++j) o1[j] = bf16_of(Ts[hc + 8 + j][lr]);
  *(short8*)dst = o0;
  *(short8*)(dst + 8) = o1;
  // s1 partial: sum over this block's 64 h of C[h][l]*w1[h]
  int q = t >> 6, lq = t & 63;
  float a = 0.f;
#pragma unroll
  for (int j = 0; j < 16; ++j) a += Ts[(q << 4) + j][lq] * w[h0 + (q << 4) + j];
  red[q][lq] = a;
  __syncthreads();
  if (q == 0)
    s1p[((size_t)blockIdx.y * NB + b) * NLC + l0 + lq] =
        red[0][lq] + red[1][lq] + red[2][lq] + red[3][lq];
}

// ---- prep: Qtw3[m][h]=bf16(Q[h][m]*w3[h]); Qb_hm=bf16(Q); s2 partials ----
__global__ __launch_bounds__(256) void k_prep_q(const float* __restrict__ Q,
                                                const float* __restrict__ w,
                                                short* __restrict__ Qtw3,
                                                short* __restrict__ Qb_hm,
                                                float* __restrict__ s2p) {
  __shared__ float Ts[64][65];
  __shared__ float red[4][64];
  int b = blockIdx.z, h0 = blockIdx.y << 6, m0 = blockIdx.x << 6;
  int t = threadIdx.x;
  int hr = t >> 4, mc = (t & 15) << 2;
  const float* w3 = w + 2 * NH;
  const float* Qb = Q + ((size_t)b * NH + h0) * NLQ + m0;
#pragma unroll
  for (int i = 0; i < 4; ++i) {
    int h = hr + i * 16;
    float w3v = w3[h0 + h];
    float4 v = *(const float4*)&Qb[(size_t)h * NLQ + mc];
    short4 qb;
    qb.x = bf16_of(v.x); qb.y = bf16_of(v.y);
    qb.z = bf16_of(v.z); qb.w = bf16_of(v.w);
    *(short4*)&Qb_hm[((size_t)b * NH + h0 + h) * NLQ + m0 + mc] = qb;
    Ts[h][mc + 0] = v.x * w3v;
    Ts[h][mc + 1] = v.y * w3v;
    Ts[h][mc + 2] = v.z * w3v;
    Ts[h][mc + 3] = v.w * w3v;
  }
  __syncthreads();
  int mr = t >> 2, hc = (t & 3) << 4;
  short* dst = &Qtw3[((size_t)b * NLQ + m0 + mr) * NH + h0 + hc];
  short8 o0, o1;
#pragma unroll
  for (int j = 0; j < 8; ++j) o0[j] = bf16_of(Ts[hc + j][mr]);
#pragma unroll
  for (int j = 0; j < 8; ++j) o1[j] = bf16_of(Ts[hc + 8 + j][mr]);
  *(short8*)dst = o0;
  *(short8*)(dst + 8) = o1;
  // s2 partial over this block's 64 h (reload raw Q; L1-hot)
  int q = t >> 6, mq = t & 63;
  const float* w2 = w + NH;
  float a = 0.f;
#pragma unroll
  for (int j = 0; j < 16; ++j) {
    int h = (q << 4) + j;
    a += Qb[(size_t)h * NLQ + mq] * w2[h0 + h];
  }
  red[q][mq] = a;
  __syncthreads();
  if (q == 0)
    s2p[((size_t)blockIdx.y * NB + b) * NLQ + m0 + mq] =
        red[0][mq] + red[1][mq] + red[2][mq] + red[3][mq];
}

// ---------------- prep: plain f32 -> bf16 copies ----------------
__global__ __launch_bounds__(256) void k_prep_bf16(const float* __restrict__ X,
                                                   short* __restrict__ Y) {
  size_t i = ((size_t)blockIdx.x * 256 + threadIdx.x) * 8;
  float4 v0 = *(const float4*)&X[i];
  float4 v1 = *(const float4*)&X[i + 4];
  *(short8*)&Y[i] = cvt8(v0, v1);
}

// ------- S = Ct_lh @ Qtw3^T + s1 + s2  (M=l, N=m, K=h); 2-phase dbuf.
// Epilogue reduces s1p/s2p partials in-register (sfin folded) and emits
// column-softmax partials straight from registers -> pmax/psum chunk = by.
__global__ __launch_bounds__(256) void k_sgemm(
    const short* __restrict__ Ct_lh, const short* __restrict__ Qtw3,
    const float* __restrict__ s1p, const float* __restrict__ s2p,
    const int* __restrict__ cmask, float* __restrict__ S,
    float* __restrict__ pmax, float* __restrict__ psum) {
  __shared__ short As[2][4096], Bs[2][4096];
  __shared__ float cmsh[128];
  __shared__ float sredm[4][4][16], sreds[4][4][16];
  XCD_SWZ(NLQ / 128, NLC / 128, NB, bx, by, bz)
  int b = bz, l0 = by << 7, m0 = bx << 7;
  GEMM_IDS
  const short* Ag = Ct_lh + ((size_t)b * NLC + l0) * NH;
  const short* Bg = Qtw3 + ((size_t)b * NLQ + m0) * NH;
  f32x4 acc[4][4] = {};
  stage_g(Ag, NH, As[0], t);
  stage_g(Bg, NH, Bs[0], t);
  __syncthreads();
  int cur = 0;
  for (int kn = 32; kn <= NH; kn += 32) {
    if (kn < NH) {
      stage_g(Ag + kn, NH, As[cur ^ 1], t);
      stage_g(Bg + kn, NH, Bs[cur ^ 1], t);
    }
    MFMA_STEP(As[cur], Bs[cur])
    __syncthreads();
    cur ^= 1;
  }
  // ---- epilogue: S write + column partials from registers ----
  if (t < 128) cmsh[t] = cmask[b * NLC + l0 + t] ? 0.f : NEGV;
  __syncthreads();
  const int N1 = NB * NLC, N2 = NB * NLQ;
  float s1r[16], ncr[16];
#pragma unroll
  for (int mi = 0; mi < 4; ++mi)
#pragma unroll
    for (int r = 0; r < 4; ++r) {
      int lloc = wr + mi * 16 + g * 4 + r;
      int gl = b * NLC + l0 + lloc;
      s1r[mi * 4 + r] =
          s1p[gl] + s1p[N1 + gl] + s1p[2 * N1 + gl] + s1p[3 * N1 + gl];
      ncr[mi * 4 + r] = cmsh[lloc];
    }
  float s2v[4], mxc[4], smc[4];
#pragma unroll
  for (int ni = 0; ni < 4; ++ni) {
    int gm = b * NLQ + m0 + wc + ni * 16 + ln;
    s2v[ni] = s2p[gm] + s2p[N2 + gm] + s2p[2 * N2 + gm] + s2p[3 * N2 + gm];
    mxc[ni] = -INFINITY;
    smc[ni] = 0.f;
  }
#pragma unroll
  for (int ni = 0; ni < 4; ++ni)
#pragma unroll
    for (int mi = 0; mi < 4; ++mi)
#pragma unroll
      for (int r = 0; r < 4; ++r)
        mxc[ni] = fmaxf(mxc[ni],
                        acc[mi][ni][r] + s1r[mi * 4 + r] + s2v[ni] +
                            ncr[mi * 4 + r]);
#pragma unroll
  for (int ni = 0; ni < 4; ++ni) {
    int m = m0 + wc + ni * 16 + ln;
#pragma unroll
    for (int mi = 0; mi < 4; ++mi)
#pragma unroll
      for (int r = 0; r < 4; ++r) {
        int l = l0 + wr + mi * 16 + g * 4 + r;
        float sv = acc[mi][ni][r] + s1r[mi * 4 + r] + s2v[ni];
        S[((size_t)b * NLC + l) * NLQ + m] = sv;
        smc[ni] += expf(sv + ncr[mi * 4 + r] - mxc[ni]);
      }
  }
  // butterfly across the 4 lane-groups (same ln, different g)
#pragma unroll
  for (int off = 16; off <= 32; off <<= 1)
#pragma unroll
    for (int ni = 0; ni < 4; ++ni) {
      float m2 = __shfl_xor(mxc[ni], off);
      float s2x = __shfl_xor(smc[ni], off);
      float nm = fmaxf(mxc[ni], m2);
      smc[ni] = smc[ni] * expf(mxc[ni] - nm) + s2x * expf(m2 - nm);
      mxc[ni] = nm;
    }
  if (lane < 16) {
#pragma unroll
    for (int ni = 0; ni < 4; ++ni) {
      sredm[w][ni][lane] = mxc[ni];
      sreds[w][ni][lane] = smc[ni];
    }
  }
  __syncthreads();
  if (t < 128) {
    int wcsel = t >> 6, nii = (t >> 4) & 3, lnn = t & 15;
    float mA = sredm[wcsel][nii][lnn], sA = sreds[wcsel][nii][lnn];
    float mB = sredm[wcsel + 2][nii][lnn], sB = sreds[wcsel + 2][nii][lnn];
    float nm = fmaxf(mA, mB);
    float sm = sA * expf(mA - nm) + sB * expf(mB - nm);
    int m = m0 + (wcsel << 6) + nii * 16 + lnn;
    size_t base = ((size_t)b * NLQ + m) * TCH + by;
    pmax[base] = nm;
    psum[base] = sm;
  }
}

// combine TCH partials per column -> cmax, cinv. One thread per column.
__global__ __launch_bounds__(256) void k_colfin(const float* __restrict__ pmax,
                                                const float* __restrict__ psum,
                                                float* __restrict__ cmax,
                                                float* __restrict__ cinv) {
  int m = blockIdx.x * 256 + threadIdx.x;  // [0, NB*NLQ)
  const float* pm = pmax + (size_t)m * TCH;
  const float* ps = psum + (size_t)m * TCH;
  float mx = pm[0], sm = ps[0];
#pragma unroll
  for (int c = 1; c < TCH; ++c) {
    float m2 = pm[c], s2 = ps[c];
    float nm = fmaxf(mx, m2);
    sm = sm * expf(mx - nm) + s2 * expf(m2 - nm);
    mx = nm;
  }
  cmax[m] = mx;
  cinv[m] = 1.0f / sm;
}

// ---- row+col softmax, IN PLACE: each 1KB f32 S row slot is replaced by
// bf16 P_row (bytes 0..511) and bf16 P_col (bytes 512..1023).
__global__ __launch_bounds__(256) void k_rowsoft(float* __restrict__ S,
                                                 const int* __restrict__ qmask,
                                                 const int* __restrict__ cmask,
                                                 const float* __restrict__ cmax,
                                                 const float* __restrict__ cinv) {
  int wave = threadIdx.x >> 6, lane = threadIdx.x & 63;
  int idx = (blockIdx.x << 2) + wave;  // row id in [0, NB*NLC)
  int b = idx >> 10;
  float* row = S + (size_t)idx * NLQ;
  const int* qm = qmask + b * NLQ;
  int m4 = lane << 2;
  float4 v = *(const float4*)&row[m4];
  int4 q = *(const int4*)&qm[m4];
  float x0 = v.x + (q.x ? 0.f : NEGV);
  float x1 = v.y + (q.y ? 0.f : NEGV);
  float x2 = v.z + (q.z ? 0.f : NEGV);
  float x3 = v.w + (q.w ? 0.f : NEGV);
  float mx = fmaxf(fmaxf(x0, x1), fmaxf(x2, x3));
#pragma unroll
  for (int off = 32; off > 0; off >>= 1) mx = fmaxf(mx, __shfl_xor(mx, off));
  float p0 = expf(x0 - mx), p1 = expf(x1 - mx);
  float p2 = expf(x2 - mx), p3 = expf(x3 - mx);
  float sm = p0 + p1 + p2 + p3;
#pragma unroll
  for (int off = 32; off > 0; off >>= 1) sm += __shfl_xor(sm, off);
  float iv = 1.0f / sm;
  short4 o;
  o.x = bf16_of(p0 * iv);
  o.y = bf16_of(p1 * iv);
  o.z = bf16_of(p2 * iv);
  o.w = bf16_of(p3 * iv);
  // col-softmax values for this row (normalized over l via cmax/cinv)
  float cmf = (float)cmask[idx];
  float4 cm4 = *(const float4*)&cmax[(b << 8) + m4];
  float4 ci4 = *(const float4*)&cinv[(b << 8) + m4];
  short4 oc;
  oc.x = bf16_of(expf(v.x - cm4.x) * ci4.x * cmf);
  oc.y = bf16_of(expf(v.y - cm4.y) * ci4.y * cmf);
  oc.z = bf16_of(expf(v.z - cm4.z) * ci4.z * cmf);
  oc.w = bf16_of(expf(v.w - cm4.w) * ci4.w * cmf);
  *(short4*)((short*)row + m4) = o;
  *(short4*)((short*)row + 256 + m4) = oc;
}

// ------ Tp[ks][b][h][m] = sum_{l in chunk ks} C[h][l] * P_col[l][m] ------
// split-K partials (f32); M=h, N=m, K=l chunk of 256.
// A: bf16 Cb_hl via stage_g (DMA). B: bf16 P_col transposed scatter.
__global__ __launch_bounds__(256) void k_tgemm(const short* __restrict__ Cb_hl,
                                               const short* __restrict__ PcolS,
                                               float* __restrict__ Tp) {
  __shared__ short As[4096], Bs[4096];
  XCD_SWZ(4, KSPLIT, NB, bx, by, bz)
  int b = bz;
  int ks = by;
  int h0 = (bx & 1) << 7;
  int m0 = (bx >> 1) << 7;
  GEMM_IDS
  const short* Ag = Cb_hl + ((size_t)b * NH + h0) * NLC;
  const short* Pb = PcolS + (size_t)b * NLC * 512 + 256 + m0;
  f32x4 acc[4][4] = {};
  int kbeg = ks * (NLC / KSPLIT), kend = kbeg + NLC / KSPLIT;
  int lloc = t >> 3, g2 = lloc >> 3, kin = lloc & 7;
  int mbase = (t & 7) << 4;
  for (int k0 = kbeg; k0 < kend; k0 += 32) {
    __syncthreads();
    stage_g(Ag + k0, NLC, As, t);
    {  // B: bf16 P_col passthrough, transposed into swizzled LDS
      const short* srow = Pb + (size_t)(k0 + lloc) * 512;
      short8 x0 = *(const short8*)&srow[mbase];
      short8 x1 = *(const short8*)&srow[mbase + 8];
#pragma unroll
      for (int j = 0; j < 8; ++j) {
        int R = mbase + j;
        int byteoff =
            (R << 6) + (((g2 ^ ((R >> 1) & 3)) & 3) << 4) + (kin << 1);
        *(short*)((char*)Bs + byteoff) = x0[j];
      }
#pragma unroll
      for (int j = 0; j < 8; ++j) {
        int R = mbase + 8 + j;
        int byteoff =
            (R << 6) + (((g2 ^ ((R >> 1) & 3)) & 3) << 4) + (kin << 1);
        *(short*)((char*)Bs + byteoff) = x1[j];
      }
    }
    __syncthreads();
    MFMA_STEP(As, Bs)
  }
  float* dst = Tp + ((size_t)ks * NB + b) * NH * NLQ;
#pragma unroll
  for (int mi = 0; mi < 4; ++mi)
#pragma unroll
    for (int ni = 0; ni < 4; ++ni)
#pragma unroll
      for (int r = 0; r < 4; ++r) {
        int h = h0 + wr + mi * 16 + g * 4 + r;
        int m = m0 + wc + ni * 16 + ln;
        dst[(size_t)h * NLQ + m] = acc[mi][ni][r];
      }
}

// reduce KSPLIT partials -> bf16 Tt[b][h][m]
__global__ __launch_bounds__(256) void k_tfin(const float* __restrict__ Tp,
                                              short* __restrict__ Tt) {
  size_t i = ((size_t)blockIdx.x * 256 + threadIdx.x) * 4;
  const size_t stride = (size_t)NB * NH * NLQ;
  float4 s = *(const float4*)&Tp[i];
#pragma unroll
  for (int ks = 1; ks < KSPLIT; ++ks) {
    float4 v = *(const float4*)&Tp[i + ks * stride];
    s.x += v.x; s.y += v.y; s.z += v.z; s.w += v.w;
  }
  short4 o;
  o.x = bf16_of(s.x);
  o.y = bf16_of(s.y);
  o.z = bf16_of(s.z);
  o.w = bf16_of(s.w);
  *(short4*)&Tt[i] = o;
}

// ---- [A | Ct*Bv][l][h] = f(sum_m P_row[l][m] * X[h][m]); 2-phase dbuf ----
__global__ __launch_bounds__(256) void k_abgemm(
    const short* __restrict__ Prow, const short* __restrict__ Qb_hm,
    const short* __restrict__ Tt, const short* __restrict__ Ct_lh,
    short* __restrict__ A_lh, short* __restrict__ CtBv_lh) {
  __shared__ short As[2][4096], Bs[2][4096];
  XCD_SWZ(4, NLC / 128, NB, bx, by, bz)
  int b = bz, l0 = by << 7, nb = bx;
  GEMM_IDS
  const short* Ag = Prow + ((size_t)b * NLC + l0) * 512;
  const short* Bbase = (nb < 2)
                           ? Qb_hm + ((size_t)b * NH + nb * 128) * NLQ
                           : Tt + ((size_t)b * NH + (nb - 2) * 128) * NLQ;
  f32x4 acc[4][4] = {};
  stage_g(Ag, 512, As[0], t);
  stage_g(Bbase, NLQ, Bs[0], t);
  __syncthreads();
  int cur = 0;
  for (int kn = 32; kn <= NLQ; kn += 32) {
    if (kn < NLQ) {
      stage_g(Ag + kn, 512, As[cur ^ 1], t);
      stage_g(Bbase + kn, NLQ, Bs[cur ^ 1], t);
    }
    MFMA_STEP(As[cur], Bs[cur])
    __syncthreads();
    cur ^= 1;
  }
  int hbase = (nb & 1) << 7;
  if (nb < 2) {
#pragma unroll
    for (int mi = 0; mi < 4; ++mi)
#pragma unroll
      for (int ni = 0; ni < 4; ++ni)
#pragma unroll
        for (int r = 0; r < 4; ++r) {
          int l = l0 + wr + mi * 16 + g * 4 + r;
          int h = hbase + wc + ni * 16 + ln;
          A_lh[((size_t)b * NLC + l) * NH + h] = bf16_of(acc[mi][ni][r]);
        }
  } else {
#pragma unroll
    for (int mi = 0; mi < 4; ++mi)
#pragma unroll
      for (int ni = 0; ni < 4; ++ni)
#pragma unroll
        for (int r = 0; r < 4; ++r) {
          int l = l0 + wr + mi * 16 + g * 4 + r;
          int h = hbase + wc + ni * 16 + ln;
          size_t off = ((size_t)b * NLC + l) * NH + h;
          CtBv_lh[off] = bf16_of(f_of(Ct_lh[off]) * acc[mi][ni][r]);
        }
  }
}

// -------- out[h][l] = relu(b + sum_f W[h][f]*cat[l][f]); 2-phase dbuf --------
// cat regions along f: [Ct | A | Ct*A | Ct*Bv]; Wb is bf16 W_res.
__global__ __launch_bounds__(256) void k_out(
    const short* __restrict__ Wb, const short* __restrict__ Ct_lh,
    const short* __restrict__ A_lh, const short* __restrict__ CtBv_lh,
    const float* __restrict__ br, float* __restrict__ out) {
  __shared__ short As[2][4096], Bs[2][4096];
  XCD_SWZ(NLC / 128, NH / 128, NB, bx, by, bz)
  int b = bz, h0 = by << 7, l0 = bx << 7;
  GEMM_IDS
  const short* Wg = Wb + (size_t)h0 * (4 * NH);
  size_t boff = ((size_t)b * NLC + l0) * NH;
  f32x4 acc[4][4] = {};
  stage_g(Wg, 4 * NH, As[0], t);
  stage_g(Ct_lh + boff, NH, Bs[0], t);  // tile 0 is region 0 (Ct)
  __syncthreads();
  int cur = 0;
  for (int kn = 32; kn <= 4 * NH; kn += 32) {
    bool has = kn < 4 * NH;
    int regn = kn >> 8, kon = kn & 255;
    short8 x1[2], x2[2];
    int ca = lane & 3;
    if (has) {
      stage_g(Wg + kn, 4 * NH, As[cur ^ 1], t);
      if (regn != 2) {
        const short* base = (regn == 0) ? Ct_lh : (regn == 1) ? A_lh : CtBv_lh;
        stage_g(base + boff + kon, NH, Bs[cur ^ 1], t);
      } else {
#pragma unroll
        for (int i = 0; i < 2; ++i) {
          int seg = w + i * 4, r = seg * 16 + (lane >> 2);
          size_t off = boff + (size_t)r * NH + kon + ca * 8;
          x1[i] = *(const short8*)&Ct_lh[off];
          x2[i] = *(const short8*)&A_lh[off];
        }
      }
    }
    MFMA_STEP(As[cur], Bs[cur])
    if (has && regn == 2) {
#pragma unroll
      for (int i = 0; i < 2; ++i) {
        int seg = w + i * 4, r = seg * 16 + (lane >> 2);
        short8 o;
#pragma unroll
        for (int j = 0; j < 8; ++j)
          o[j] = bf16_of(f_of(x1[i][j]) * f_of(x2[i][j]));
        lds_w8(Bs[cur ^ 1], r, ca, o);
      }
    }
    __syncthreads();
    cur ^= 1;
  }
#pragma unroll
  for (int mi = 0; mi < 4; ++mi)
#pragma unroll
    for (int ni = 0; ni < 4; ++ni) {
      int h = h0 + wr + mi * 16 + g * 4;
      int l = l0 + wc + ni * 16 + ln;
#pragma unroll
      for (int r = 0; r < 4; ++r) {
        float bias = br[h + r];
        out[((size_t)b * NH + h + r) * NLC + l] =
            fmaxf(acc[mi][ni][r] + bias, 0.f);
      }
    }
}

extern "C" void kernel_launch(void* const* d_in, const int* in_sizes, int n_in,
                              void* d_out, int out_size, void* d_ws,
                              size_t ws_size, hipStream_t stream) {
  (void)in_sizes;
  (void)n_in;
  (void)out_size;
  (void)ws_size;
  const float* C = (const float*)d_in[0];
  const float* Q = (const float*)d_in[1];
  const int* cmask = (const int*)d_in[2];
  const int* qmask = (const int*)d_in[3];
  const float* w = (const float*)d_in[4];
  const float* W = (const float*)d_in[5];
  const float* br = (const float*)d_in[6];
  float* out = (float*)d_out;

  char* p = (char*)d_ws;
  float* S = (float*)p;       p += (size_t)NB * NLC * NLQ * 4;   // 33.6 MB
  short* Ct_lh = (short*)p;   p += (size_t)NB * NLC * NH * 2;    // 16.8 MB
  short* A_lh = (short*)p;    p += (size_t)NB * NLC * NH * 2;    // 16.8 MB
  short* CtBv_lh = (short*)p; p += (size_t)NB * NLC * NH * 2;    // 16.8 MB
  short* Cb_hl = (short*)p;   p += (size_t)NB * NH * NLC * 2;    // 16.8 MB
  short* Tt = (short*)p;      p += (size_t)NB * NH * NLQ * 2;    // 4.2 MB
  short* Qtw3 = (short*)p;    p += (size_t)NB * NLQ * NH * 2;    // 4.2 MB
  short* Qb_hm = (short*)p;   p += (size_t)NB * NH * NLQ * 2;    // 4.2 MB
  short* Wb = (short*)p;      p += (size_t)NH * 4 * NH * 2;      // 0.5 MB
  float* cmax = (float*)p;    p += (size_t)NB * NLQ * 4;
  float* cinv = (float*)p;    p += (size_t)NB * NLQ * 4;
  float* pmax = (float*)p;    p += (size_t)NB * NLQ * TCH * 4;
  float* psum = (float*)p;    p += (size_t)NB * NLQ * TCH * 4;
  float* s1p = (float*)p;     p += (size_t)4 * NB * NLC * 4;     // 0.5 MB
  float* s2p = (float*)p;     p += (size_t)4 * NB * NLQ * 4;     // 0.13 MB
  // tgemm split-K partials: reuse A_lh+CtBv_lh (33.6 MB, dead until abgemm).
  float* Tp = (float*)A_lh;
  // in-place softmax: bf16 P_row at bytes 0..511, P_col at 512..1023 of each
  // 1KB S row (row stride 512 shorts).
  short* Prow = (short*)S;

  k_prep_c<<<dim3(NLC / 64, NH / 64, NB), dim3(256), 0, stream>>>(C, w, Ct_lh,
                                                                  Cb_hl, s1p);
  k_prep_q<<<dim3(NLQ / 64, NH / 64, NB), dim3(256), 0, stream>>>(
      Q, w, Qtw3, Qb_hm, s2p);
  k_prep_bf16<<<dim3(NH * 4 * NH / 2048), dim3(256), 0, stream>>>(W, Wb);
  k_sgemm<<<dim3(NLQ / 128, NLC / 128, NB), dim3(256), 0, stream>>>(
      Ct_lh, Qtw3, s1p, s2p, cmask, S, pmax, psum);
  k_colfin<<<dim3(NB * NLQ / 256), dim3(256), 0, stream>>>(pmax, psum, cmax,
                                                           cinv);
  k_rowsoft<<<dim3(NB * NLC / 4), dim3(256), 0, stream>>>(S, qmask, cmask,
                                                          cmax, cinv);
  k_tgemm<<<dim3(4, KSPLIT, NB), dim3(256), 0, stream>>>(Cb_hl, Prow, Tp);
  k_tfin<<<dim3(NB * NH * NLQ / 1024), dim3(256), 0, stream>>>(Tp, Tt);
  k_abgemm<<<dim3(4, NLC / 128, NB), dim3(256), 0, stream>>>(
      Prow, Qb_hm, Tt, Ct_lh, A_lh, CtBv_lh);
  k_out<<<dim3(NLC / 128, NH / 128, NB), dim3(256), 0, stream>>>(
      Wb, Ct_lh, A_lh, CtBv_lh, br, out);
}

// Round 11
// 139.170 us; speedup vs baseline: 1.2860x; 1.0327x over previous
//
#include <hip/hip_runtime.h>
#include <math.h>

#define NB 32
#define NH 256
#define NLC 1024
#define NLQ 256
#define NEGV (-1e30f)
#define TCH 8      // column-stats l-chunks (each 128 rows, = sgemm l-tile)
#define KSPLIT 4   // tgemm split-K factor

typedef short short8 __attribute__((ext_vector_type(8)));
typedef float f32x4 __attribute__((ext_vector_type(4)));

__device__ inline short bf16_of(float f) {
  union { float f; unsigned u; } v;
  v.f = f;
  unsigned r = (v.u + 0x7fffu + ((v.u >> 16) & 1u)) >> 16;
  return (short)r;
}
__device__ inline float f_of(short s) {
  union { unsigned u; float f; } v;
  v.u = ((unsigned)(unsigned short)s) << 16;
  return v.f;
}
__device__ inline short8 cvt8(float4 a, float4 b) {
  short8 o;
  o[0] = bf16_of(a.x); o[1] = bf16_of(a.y); o[2] = bf16_of(a.z); o[3] = bf16_of(a.w);
  o[4] = bf16_of(b.x); o[5] = bf16_of(b.y); o[6] = bf16_of(b.z); o[7] = bf16_of(b.w);
  return o;
}

// XCD-aware bijective block swizzle (T1): consecutive logical tiles land on
// the same XCD's L2 so operand-sharing neighbor blocks hit instead of miss.
// Requires nwg % 8 == 0 (all our GEMM grids are).
#define XCD_SWZ(GX, GY, GZ, bx, by, bz)                                 \
  int bx, by, bz;                                                       \
  {                                                                     \
    int _lin = blockIdx.x + (GX) * (blockIdx.y + (GY) * blockIdx.z);    \
    const int _nwg = (GX) * (GY) * (GZ);                                \
    _lin = (_lin & 7) * (_nwg >> 3) + (_lin >> 3);                      \
    bx = _lin % (GX);                                                   \
    by = (_lin / (GX)) % (GY);                                          \
    bz = _lin / ((GX) * (GY));                                          \
  }

// ---- swizzled 128x32 bf16 LDS tile helpers (row = 64B, slot ^= (row>>1)&3) ----
__device__ inline void lds_w8(short* lds, int r, int c, short8 v) {
  int byteoff = (r << 6) + (((c ^ ((r >> 1) & 3)) & 3) << 4);
  *(short8*)((char*)lds + byteoff) = v;
}
__device__ inline short8 lds_r8(const short* lds, int R, int g) {
  int byteoff = (R << 6) + (((g ^ ((R >> 1) & 3)) & 3) << 4);
  return *(const short8*)((const char*)lds + byteoff);
}
// global_load_lds staging of a 128x32 bf16 tile from K-minor src (ld elements).
// Source group pre-permuted per-lane so linear LDS bytes match swizzled reads.
__device__ inline void stage_g(const short* src, int ld, short* lds, int t) {
  int L = t & 63, w = t >> 6;
  int cp = (L & 3) ^ ((L >> 3) & 3);
#pragma unroll
  for (int i = 0; i < 2; ++i) {
    int seg = w + i * 4;
    const short* g = src + (size_t)(seg * 16 + (L >> 2)) * ld + cp * 8;
    __builtin_amdgcn_global_load_lds(
        (const __attribute__((address_space(1))) unsigned int*)g,
        (__attribute__((address_space(3))) unsigned int*)(lds + seg * 512), 16,
        0, 0);
  }
}

#define GEMM_IDS                                       \
  int t = threadIdx.x, lane = t & 63, w = t >> 6;      \
  int ln = lane & 15, g = lane >> 4;                   \
  int wr = (w >> 1) << 6, wc = (w & 1) << 6;           \
  (void)wr; (void)wc;

#define MFMA_STEP(AS, BS)                                                      \
  {                                                                            \
    short8 af[4], bfr[4];                                                      \
    _Pragma("unroll") for (int mi = 0; mi < 4; ++mi) af[mi] =                  \
        lds_r8(AS, wr + mi * 16 + ln, g);                                      \
    _Pragma("unroll") for (int ni = 0; ni < 4; ++ni) bfr[ni] =                 \
        lds_r8(BS, wc + ni * 16 + ln, g);                                      \
    _Pragma("unroll") for (int mi = 0; mi < 4; ++mi)                           \
        _Pragma("unroll") for (int ni = 0; ni < 4; ++ni) acc[mi][ni] =         \
            __builtin_amdgcn_mfma_f32_16x16x32_bf16(af[mi], bfr[ni],           \
                                                    acc[mi][ni], 0, 0, 0);     \
  }

// -- prep: Ct_lh[l][h] = bf16(C[h][l]); Cb_hl[h][l] = bf16(C); s1 partials --
__global__ __launch_bounds__(256) void k_prep_c(const float* __restrict__ C,
                                                const float* __restrict__ w,
                                                short* __restrict__ Ct_lh,
                                                short* __restrict__ Cb_hl,
                                                float* __restrict__ s1p) {
  __shared__ float Ts[64][65];
  __shared__ float red[4][64];
  int b = blockIdx.z, h0 = blockIdx.y << 6, l0 = blockIdx.x << 6;
  int t = threadIdx.x;
  int hr = t >> 4, lc = (t & 15) << 2;
  const float* Cb = C + ((size_t)b * NH + h0) * NLC + l0;
#pragma unroll
  for (int i = 0; i < 4; ++i) {
    int h = hr + i * 16;
    float4 v = *(const float4*)&Cb[(size_t)h * NLC + lc];
    short4 cb;
    cb.x = bf16_of(v.x); cb.y = bf16_of(v.y);
    cb.z = bf16_of(v.z); cb.w = bf16_of(v.w);
    *(short4*)&Cb_hl[((size_t)b * NH + h0 + h) * NLC + l0 + lc] = cb;
    Ts[h][lc + 0] = v.x;
    Ts[h][lc + 1] = v.y;
    Ts[h][lc + 2] = v.z;
    Ts[h][lc + 3] = v.w;
  }
  __syncthreads();
  int lr = t >> 2, hc = (t & 3) << 4;
  short* dst = &Ct_lh[((size_t)b * NLC + l0 + lr) * NH + h0 + hc];
  short8 o0, o1;
#pragma unroll
  for (int j = 0; j < 8; ++j) o0[j] = bf16_of(Ts[hc + j][lr]);
#pragma unroll
  for (int j = 0; j < 8; ++j) o1[j] = bf16_of(Ts[hc + 8 + j][lr]);
  *(short8*)dst = o0;
  *(short8*)(dst + 8) = o1;
  // s1 partial: sum over this block's 64 h of C[h][l]*w1[h]
  int q = t >> 6, lq = t & 63;
  float a = 0.f;
#pragma unroll
  for (int j = 0; j < 16; ++j) a += Ts[(q << 4) + j][lq] * w[h0 + (q << 4) + j];
  red[q][lq] = a;
  __syncthreads();
  if (q == 0)
    s1p[((size_t)blockIdx.y * NB + b) * NLC + l0 + lq] =
        red[0][lq] + red[1][lq] + red[2][lq] + red[3][lq];
}

// ---- prep: Qtw3[m][h]=bf16(Q[h][m]*w3[h]); Qb_hm=bf16(Q); s2 partials ----
// Ts holds RAW Q; w3 is applied during the transposed write.
__global__ __launch_bounds__(256) void k_prep_q(const float* __restrict__ Q,
                                                const float* __restrict__ w,
                                                short* __restrict__ Qtw3,
                                                short* __restrict__ Qb_hm,
                                                float* __restrict__ s2p) {
  __shared__ float Ts[64][65];
  __shared__ float red[4][64];
  int b = blockIdx.z, h0 = blockIdx.y << 6, m0 = blockIdx.x << 6;
  int t = threadIdx.x;
  int hr = t >> 4, mc = (t & 15) << 2;
  const float* w3 = w + 2 * NH;
  const float* Qb = Q + ((size_t)b * NH + h0) * NLQ + m0;
#pragma unroll
  for (int i = 0; i < 4; ++i) {
    int h = hr + i * 16;
    float4 v = *(const float4*)&Qb[(size_t)h * NLQ + mc];
    short4 qb;
    qb.x = bf16_of(v.x); qb.y = bf16_of(v.y);
    qb.z = bf16_of(v.z); qb.w = bf16_of(v.w);
    *(short4*)&Qb_hm[((size_t)b * NH + h0 + h) * NLQ + m0 + mc] = qb;
    Ts[h][mc + 0] = v.x;
    Ts[h][mc + 1] = v.y;
    Ts[h][mc + 2] = v.z;
    Ts[h][mc + 3] = v.w;
  }
  __syncthreads();
  int mr = t >> 2, hc = (t & 3) << 4;
  short* dst = &Qtw3[((size_t)b * NLQ + m0 + mr) * NH + h0 + hc];
  short8 o0, o1;
#pragma unroll
  for (int j = 0; j < 8; ++j)
    o0[j] = bf16_of(Ts[hc + j][mr] * w3[h0 + hc + j]);
#pragma unroll
  for (int j = 0; j < 8; ++j)
    o1[j] = bf16_of(Ts[hc + 8 + j][mr] * w3[h0 + hc + 8 + j]);
  *(short8*)dst = o0;
  *(short8*)(dst + 8) = o1;
  // s2 partial over this block's 64 h, straight from the raw-Q LDS tile
  int q = t >> 6, mq = t & 63;
  const float* w2 = w + NH;
  float a = 0.f;
#pragma unroll
  for (int j = 0; j < 16; ++j)
    a += Ts[(q << 4) + j][mq] * w2[h0 + (q << 4) + j];
  red[q][mq] = a;
  __syncthreads();
  if (q == 0)
    s2p[((size_t)blockIdx.y * NB + b) * NLQ + m0 + mq] =
        red[0][mq] + red[1][mq] + red[2][mq] + red[3][mq];
}

// ---------------- prep: plain f32 -> bf16 copies ----------------
__global__ __launch_bounds__(256) void k_prep_bf16(const float* __restrict__ X,
                                                   short* __restrict__ Y) {
  size_t i = ((size_t)blockIdx.x * 256 + threadIdx.x) * 8;
  float4 v0 = *(const float4*)&X[i];
  float4 v1 = *(const float4*)&X[i + 4];
  *(short8*)&Y[i] = cvt8(v0, v1);
}

// ------- S = Ct_lh @ Qtw3^T + s1 + s2  (M=l, N=m, K=h); 2-phase dbuf.
// Epilogue reduces s1p/s2p partials in-register (sfin folded) and emits
// column-softmax partials straight from registers -> pmax/psum chunk = by.
__global__ __launch_bounds__(256) void k_sgemm(
    const short* __restrict__ Ct_lh, const short* __restrict__ Qtw3,
    const float* __restrict__ s1p, const float* __restrict__ s2p,
    const int* __restrict__ cmask, float* __restrict__ S,
    float* __restrict__ pmax, float* __restrict__ psum) {
  __shared__ short As[2][4096], Bs[2][4096];
  __shared__ float cmsh[128];
  __shared__ float sredm[4][4][16], sreds[4][4][16];
  XCD_SWZ(NLQ / 128, NLC / 128, NB, bx, by, bz)
  int b = bz, l0 = by << 7, m0 = bx << 7;
  GEMM_IDS
  const short* Ag = Ct_lh + ((size_t)b * NLC + l0) * NH;
  const short* Bg = Qtw3 + ((size_t)b * NLQ + m0) * NH;
  f32x4 acc[4][4] = {};
  stage_g(Ag, NH, As[0], t);
  stage_g(Bg, NH, Bs[0], t);
  __syncthreads();
  int cur = 0;
  for (int kn = 32; kn <= NH; kn += 32) {
    if (kn < NH) {
      stage_g(Ag + kn, NH, As[cur ^ 1], t);
      stage_g(Bg + kn, NH, Bs[cur ^ 1], t);
    }
    MFMA_STEP(As[cur], Bs[cur])
    __syncthreads();
    cur ^= 1;
  }
  // ---- epilogue: S write + column partials from registers ----
  if (t < 128) cmsh[t] = cmask[b * NLC + l0 + t] ? 0.f : NEGV;
  __syncthreads();
  const int N1 = NB * NLC, N2 = NB * NLQ;
  float s1r[16], ncr[16];
#pragma unroll
  for (int mi = 0; mi < 4; ++mi)
#pragma unroll
    for (int r = 0; r < 4; ++r) {
      int lloc = wr + mi * 16 + g * 4 + r;
      int gl = b * NLC + l0 + lloc;
      s1r[mi * 4 + r] =
          s1p[gl] + s1p[N1 + gl] + s1p[2 * N1 + gl] + s1p[3 * N1 + gl];
      ncr[mi * 4 + r] = cmsh[lloc];
    }
  float s2v[4], mxc[4], smc[4];
#pragma unroll
  for (int ni = 0; ni < 4; ++ni) {
    int gm = b * NLQ + m0 + wc + ni * 16 + ln;
    s2v[ni] = s2p[gm] + s2p[N2 + gm] + s2p[2 * N2 + gm] + s2p[3 * N2 + gm];
    mxc[ni] = -INFINITY;
    smc[ni] = 0.f;
  }
#pragma unroll
  for (int ni = 0; ni < 4; ++ni)
#pragma unroll
    for (int mi = 0; mi < 4; ++mi)
#pragma unroll
      for (int r = 0; r < 4; ++r)
        mxc[ni] = fmaxf(mxc[ni],
                        acc[mi][ni][r] + s1r[mi * 4 + r] + s2v[ni] +
                            ncr[mi * 4 + r]);
#pragma unroll
  for (int ni = 0; ni < 4; ++ni) {
    int m = m0 + wc + ni * 16 + ln;
#pragma unroll
    for (int mi = 0; mi < 4; ++mi)
#pragma unroll
      for (int r = 0; r < 4; ++r) {
        int l = l0 + wr + mi * 16 + g * 4 + r;
        float sv = acc[mi][ni][r] + s1r[mi * 4 + r] + s2v[ni];
        S[((size_t)b * NLC + l) * NLQ + m] = sv;
        smc[ni] += expf(sv + ncr[mi * 4 + r] - mxc[ni]);
      }
  }
  // butterfly across the 4 lane-groups (same ln, different g)
#pragma unroll
  for (int off = 16; off <= 32; off <<= 1)
#pragma unroll
    for (int ni = 0; ni < 4; ++ni) {
      float m2 = __shfl_xor(mxc[ni], off);
      float s2x = __shfl_xor(smc[ni], off);
      float nm = fmaxf(mxc[ni], m2);
      smc[ni] = smc[ni] * expf(mxc[ni] - nm) + s2x * expf(m2 - nm);
      mxc[ni] = nm;
    }
  if (lane < 16) {
#pragma unroll
    for (int ni = 0; ni < 4; ++ni) {
      sredm[w][ni][lane] = mxc[ni];
      sreds[w][ni][lane] = smc[ni];
    }
  }
  __syncthreads();
  if (t < 128) {
    int wcsel = t >> 6, nii = (t >> 4) & 3, lnn = t & 15;
    float mA = sredm[wcsel][nii][lnn], sA = sreds[wcsel][nii][lnn];
    float mB = sredm[wcsel + 2][nii][lnn], sB = sreds[wcsel + 2][nii][lnn];
    float nm = fmaxf(mA, mB);
    float sm = sA * expf(mA - nm) + sB * expf(mB - nm);
    int m = m0 + (wcsel << 6) + nii * 16 + lnn;
    size_t base = ((size_t)b * NLQ + m) * TCH + by;
    pmax[base] = nm;
    psum[base] = sm;
  }
}

// combine TCH partials per column -> cmax, cinv. One thread per column.
__global__ __launch_bounds__(256) void k_colfin(const float* __restrict__ pmax,
                                                const float* __restrict__ psum,
                                                float* __restrict__ cmax,
                                                float* __restrict__ cinv) {
  int m = blockIdx.x * 256 + threadIdx.x;  // [0, NB*NLQ)
  const float* pm = pmax + (size_t)m * TCH;
  const float* ps = psum + (size_t)m * TCH;
  float mx = pm[0], sm = ps[0];
#pragma unroll
  for (int c = 1; c < TCH; ++c) {
    float m2 = pm[c], s2 = ps[c];
    float nm = fmaxf(mx, m2);
    sm = sm * expf(mx - nm) + s2 * expf(m2 - nm);
    mx = nm;
  }
  cmax[m] = mx;
  cinv[m] = 1.0f / sm;
}

// ---- row+col softmax, IN PLACE: each 1KB f32 S row slot is replaced by
// bf16 P_row (bytes 0..511) and bf16 P_col (bytes 512..1023).
__global__ __launch_bounds__(256) void k_rowsoft(float* __restrict__ S,
                                                 const int* __restrict__ qmask,
                                                 const int* __restrict__ cmask,
                                                 const float* __restrict__ cmax,
                                                 const float* __restrict__ cinv) {
  int wave = threadIdx.x >> 6, lane = threadIdx.x & 63;
  int idx = (blockIdx.x << 2) + wave;  // row id in [0, NB*NLC)
  int b = idx >> 10;
  float* row = S + (size_t)idx * NLQ;
  const int* qm = qmask + b * NLQ;
  int m4 = lane << 2;
  float4 v = *(const float4*)&row[m4];
  int4 q = *(const int4*)&qm[m4];
  float x0 = v.x + (q.x ? 0.f : NEGV);
  float x1 = v.y + (q.y ? 0.f : NEGV);
  float x2 = v.z + (q.z ? 0.f : NEGV);
  float x3 = v.w + (q.w ? 0.f : NEGV);
  float mx = fmaxf(fmaxf(x0, x1), fmaxf(x2, x3));
#pragma unroll
  for (int off = 32; off > 0; off >>= 1) mx = fmaxf(mx, __shfl_xor(mx, off));
  float p0 = expf(x0 - mx), p1 = expf(x1 - mx);
  float p2 = expf(x2 - mx), p3 = expf(x3 - mx);
  float sm = p0 + p1 + p2 + p3;
#pragma unroll
  for (int off = 32; off > 0; off >>= 1) sm += __shfl_xor(sm, off);
  float iv = 1.0f / sm;
  short4 o;
  o.x = bf16_of(p0 * iv);
  o.y = bf16_of(p1 * iv);
  o.z = bf16_of(p2 * iv);
  o.w = bf16_of(p3 * iv);
  // col-softmax values for this row (normalized over l via cmax/cinv)
  float cmf = (float)cmask[idx];
  float4 cm4 = *(const float4*)&cmax[(b << 8) + m4];
  float4 ci4 = *(const float4*)&cinv[(b << 8) + m4];
  short4 oc;
  oc.x = bf16_of(expf(v.x - cm4.x) * ci4.x * cmf);
  oc.y = bf16_of(expf(v.y - cm4.y) * ci4.y * cmf);
  oc.z = bf16_of(expf(v.z - cm4.z) * ci4.z * cmf);
  oc.w = bf16_of(expf(v.w - cm4.w) * ci4.w * cmf);
  *(short4*)((short*)row + m4) = o;
  *(short4*)((short*)row + 256 + m4) = oc;
}

// ------ Tp[ks][b][h][m] = sum_{l in chunk ks} C[h][l] * P_col[l][m] ------
// split-K partials (f32); M=h, N=m, K=l chunk of 256.
// A: bf16 Cb_hl via stage_g (DMA). B: bf16 P_col transposed scatter.
__global__ __launch_bounds__(256) void k_tgemm(const short* __restrict__ Cb_hl,
                                               const short* __restrict__ PcolS,
                                               float* __restrict__ Tp) {
  __shared__ short As[4096], Bs[4096];
  XCD_SWZ(4, KSPLIT, NB, bx, by, bz)
  int b = bz;
  int ks = by;
  int h0 = (bx & 1) << 7;
  int m0 = (bx >> 1) << 7;
  GEMM_IDS
  const short* Ag = Cb_hl + ((size_t)b * NH + h0) * NLC;
  const short* Pb = PcolS + (size_t)b * NLC * 512 + 256 + m0;
  f32x4 acc[4][4] = {};
  int kbeg = ks * (NLC / KSPLIT), kend = kbeg + NLC / KSPLIT;
  int lloc = t >> 3, g2 = lloc >> 3, kin = lloc & 7;
  int mbase = (t & 7) << 4;
  for (int k0 = kbeg; k0 < kend; k0 += 32) {
    __syncthreads();
    stage_g(Ag + k0, NLC, As, t);
    {  // B: bf16 P_col passthrough, transposed into swizzled LDS
      const short* srow = Pb + (size_t)(k0 + lloc) * 512;
      short8 x0 = *(const short8*)&srow[mbase];
      short8 x1 = *(const short8*)&srow[mbase + 8];
#pragma unroll
      for (int j = 0; j < 8; ++j) {
        int R = mbase + j;
        int byteoff =
            (R << 6) + (((g2 ^ ((R >> 1) & 3)) & 3) << 4) + (kin << 1);
        *(short*)((char*)Bs + byteoff) = x0[j];
      }
#pragma unroll
      for (int j = 0; j < 8; ++j) {
        int R = mbase + 8 + j;
        int byteoff =
            (R << 6) + (((g2 ^ ((R >> 1) & 3)) & 3) << 4) + (kin << 1);
        *(short*)((char*)Bs + byteoff) = x1[j];
      }
    }
    __syncthreads();
    MFMA_STEP(As, Bs)
  }
  float* dst = Tp + ((size_t)ks * NB + b) * NH * NLQ;
#pragma unroll
  for (int mi = 0; mi < 4; ++mi)
#pragma unroll
    for (int ni = 0; ni < 4; ++ni)
#pragma unroll
      for (int r = 0; r < 4; ++r) {
        int h = h0 + wr + mi * 16 + g * 4 + r;
        int m = m0 + wc + ni * 16 + ln;
        dst[(size_t)h * NLQ + m] = acc[mi][ni][r];
      }
}

// reduce KSPLIT partials -> bf16 Tt[b][h][m]
__global__ __launch_bounds__(256) void k_tfin(const float* __restrict__ Tp,
                                              short* __restrict__ Tt) {
  size_t i = ((size_t)blockIdx.x * 256 + threadIdx.x) * 4;
  const size_t stride = (size_t)NB * NH * NLQ;
  float4 s = *(const float4*)&Tp[i];
#pragma unroll
  for (int ks = 1; ks < KSPLIT; ++ks) {
    float4 v = *(const float4*)&Tp[i + ks * stride];
    s.x += v.x; s.y += v.y; s.z += v.z; s.w += v.w;
  }
  short4 o;
  o.x = bf16_of(s.x);
  o.y = bf16_of(s.y);
  o.z = bf16_of(s.z);
  o.w = bf16_of(s.w);
  *(short4*)&Tt[i] = o;
}

// ---- [A | Ct*Bv][l][h] = f(sum_m P_row[l][m] * X[h][m]); 2-phase dbuf.
// nb<2 epilogue ALSO writes CtA_lh = Ct*A so k_out stages it via pure DMA.
__global__ __launch_bounds__(256) void k_abgemm(
    const short* __restrict__ Prow, const short* __restrict__ Qb_hm,
    const short* __restrict__ Tt, const short* __restrict__ Ct_lh,
    short* __restrict__ A_lh, short* __restrict__ CtA_lh,
    short* __restrict__ CtBv_lh) {
  __shared__ short As[2][4096], Bs[2][4096];
  XCD_SWZ(4, NLC / 128, NB, bx, by, bz)
  int b = bz, l0 = by << 7, nb = bx;
  GEMM_IDS
  const short* Ag = Prow + ((size_t)b * NLC + l0) * 512;
  const short* Bbase = (nb < 2)
                           ? Qb_hm + ((size_t)b * NH + nb * 128) * NLQ
                           : Tt + ((size_t)b * NH + (nb - 2) * 128) * NLQ;
  f32x4 acc[4][4] = {};
  stage_g(Ag, 512, As[0], t);
  stage_g(Bbase, NLQ, Bs[0], t);
  __syncthreads();
  int cur = 0;
  for (int kn = 32; kn <= NLQ; kn += 32) {
    if (kn < NLQ) {
      stage_g(Ag + kn, 512, As[cur ^ 1], t);
      stage_g(Bbase + kn, NLQ, Bs[cur ^ 1], t);
    }
    MFMA_STEP(As[cur], Bs[cur])
    __syncthreads();
    cur ^= 1;
  }
  int hbase = (nb & 1) << 7;
  if (nb < 2) {
#pragma unroll
    for (int mi = 0; mi < 4; ++mi)
#pragma unroll
      for (int ni = 0; ni < 4; ++ni)
#pragma unroll
        for (int r = 0; r < 4; ++r) {
          int l = l0 + wr + mi * 16 + g * 4 + r;
          int h = hbase + wc + ni * 16 + ln;
          size_t off = ((size_t)b * NLC + l) * NH + h;
          float a = acc[mi][ni][r];
          A_lh[off] = bf16_of(a);
          CtA_lh[off] = bf16_of(f_of(Ct_lh[off]) * a);
        }
  } else {
#pragma unroll
    for (int mi = 0; mi < 4; ++mi)
#pragma unroll
      for (int ni = 0; ni < 4; ++ni)
#pragma unroll
        for (int r = 0; r < 4; ++r) {
          int l = l0 + wr + mi * 16 + g * 4 + r;
          int h = hbase + wc + ni * 16 + ln;
          size_t off = ((size_t)b * NLC + l) * NH + h;
          CtBv_lh[off] = bf16_of(f_of(Ct_lh[off]) * acc[mi][ni][r]);
        }
  }
}

// -------- out[h][l] = relu(b + sum_f W[h][f]*cat[l][f]); 2-phase dbuf --------
// cat regions along f: [Ct | A | Ct*A | Ct*Bv] -- ALL pure stage_g DMA now.
__global__ __launch_bounds__(256) void k_out(
    const short* __restrict__ Wb, const short* __restrict__ Ct_lh,
    const short* __restrict__ A_lh, const short* __restrict__ CtA_lh,
    const short* __restrict__ CtBv_lh, const float* __restrict__ br,
    float* __restrict__ out) {
  __shared__ short As[2][4096], Bs[2][4096];
  XCD_SWZ(NLC / 128, NH / 128, NB, bx, by, bz)
  int b = bz, h0 = by << 7, l0 = bx << 7;
  GEMM_IDS
  const short* Wg = Wb + (size_t)h0 * (4 * NH);
  size_t boff = ((size_t)b * NLC + l0) * NH;
  f32x4 acc[4][4] = {};
  stage_g(Wg, 4 * NH, As[0], t);
  stage_g(Ct_lh + boff, NH, Bs[0], t);  // tile 0 is region 0 (Ct)
  __syncthreads();
  int cur = 0;
  for (int kn = 32; kn <= 4 * NH; kn += 32) {
    bool has = kn < 4 * NH;
    if (has) {
      stage_g(Wg + kn, 4 * NH, As[cur ^ 1], t);
      int regn = kn >> 8, kon = kn & 255;
      const short* base = (regn == 0) ? Ct_lh
                          : (regn == 1) ? A_lh
                          : (regn == 2) ? CtA_lh : CtBv_lh;
      stage_g(base + boff + kon, NH, Bs[cur ^ 1], t);
    }
    MFMA_STEP(As[cur], Bs[cur])
    __syncthreads();
    cur ^= 1;
  }
#pragma unroll
  for (int mi = 0; mi < 4; ++mi)
#pragma unroll
    for (int ni = 0; ni < 4; ++ni) {
      int h = h0 + wr + mi * 16 + g * 4;
      int l = l0 + wc + ni * 16 + ln;
#pragma unroll
      for (int r = 0; r < 4; ++r) {
        float bias = br[h + r];
        out[((size_t)b * NH + h + r) * NLC + l] =
            fmaxf(acc[mi][ni][r] + bias, 0.f);
      }
    }
}

extern "C" void kernel_launch(void* const* d_in, const int* in_sizes, int n_in,
                              void* d_out, int out_size, void* d_ws,
                              size_t ws_size, hipStream_t stream) {
  (void)in_sizes;
  (void)n_in;
  (void)out_size;
  (void)ws_size;
  const float* C = (const float*)d_in[0];
  const float* Q = (const float*)d_in[1];
  const int* cmask = (const int*)d_in[2];
  const int* qmask = (const int*)d_in[3];
  const float* w = (const float*)d_in[4];
  const float* W = (const float*)d_in[5];
  const float* br = (const float*)d_in[6];
  float* out = (float*)d_out;

  char* p = (char*)d_ws;
  float* S = (float*)p;       p += (size_t)NB * NLC * NLQ * 4;   // 33.6 MB
  short* Ct_lh = (short*)p;   p += (size_t)NB * NLC * NH * 2;    // 16.8 MB
  short* A_lh = (short*)p;    p += (size_t)NB * NLC * NH * 2;    // 16.8 MB
  short* CtBv_lh = (short*)p; p += (size_t)NB * NLC * NH * 2;    // 16.8 MB
  short* CtA_lh = (short*)p;  p += (size_t)NB * NLC * NH * 2;    // 16.8 MB
  short* Cb_hl = (short*)p;   p += (size_t)NB * NH * NLC * 2;    // 16.8 MB
  short* Tt = (short*)p;      p += (size_t)NB * NH * NLQ * 2;    // 4.2 MB
  short* Qtw3 = (short*)p;    p += (size_t)NB * NLQ * NH * 2;    // 4.2 MB
  short* Qb_hm = (short*)p;   p += (size_t)NB * NH * NLQ * 2;    // 4.2 MB
  short* Wb = (short*)p;      p += (size_t)NH * 4 * NH * 2;      // 0.5 MB
  float* cmax = (float*)p;    p += (size_t)NB * NLQ * 4;
  float* cinv = (float*)p;    p += (size_t)NB * NLQ * 4;
  float* pmax = (float*)p;    p += (size_t)NB * NLQ * TCH * 4;
  float* psum = (float*)p;    p += (size_t)NB * NLQ * TCH * 4;
  float* s1p = (float*)p;     p += (size_t)4 * NB * NLC * 4;     // 0.5 MB
  float* s2p = (float*)p;     p += (size_t)4 * NB * NLQ * 4;     // 0.13 MB
  // tgemm split-K partials: reuse A_lh+CtBv_lh (33.6 MB, dead until abgemm).
  float* Tp = (float*)A_lh;
  // in-place softmax: bf16 P_row at bytes 0..511, P_col at 512..1023 of each
  // 1KB S row (row stride 512 shorts).
  short* Prow = (short*)S;

  k_prep_c<<<dim3(NLC / 64, NH / 64, NB), dim3(256), 0, stream>>>(C, w, Ct_lh,
                                                                  Cb_hl, s1p);
  k_prep_q<<<dim3(NLQ / 64, NH / 64, NB), dim3(256), 0, stream>>>(
      Q, w, Qtw3, Qb_hm, s2p);
  k_prep_bf16<<<dim3(NH * 4 * NH / 2048), dim3(256), 0, stream>>>(W, Wb);
  k_sgemm<<<dim3(NLQ / 128, NLC / 128, NB), dim3(256), 0, stream>>>(
      Ct_lh, Qtw3, s1p, s2p, cmask, S, pmax, psum);
  k_colfin<<<dim3(NB * NLQ / 256), dim3(256), 0, stream>>>(pmax, psum, cmax,
                                                           cinv);
  k_rowsoft<<<dim3(NB * NLC / 4), dim3(256), 0, stream>>>(S, qmask, cmask,
                                                          cmax, cinv);
  k_tgemm<<<dim3(4, KSPLIT, NB), dim3(256), 0, stream>>>(Cb_hl, Prow, Tp);
  k_tfin<<<dim3(NB * NH * NLQ / 1024), dim3(256), 0, stream>>>(Tp, Tt);
  k_abgemm<<<dim3(4, NLC / 128, NB), dim3(256), 0, stream>>>(
      Prow, Qb_hm, Tt, Ct_lh, A_lh, CtA_lh, CtBv_lh);
  k_out<<<dim3(NLC / 128, NH / 128, NB), dim3(256), 0, stream>>>(
      Wb, Ct_lh, A_lh, CtA_lh, CtBv_lh, br, out);
}